// Round 5
// baseline (815.643 us; speedup 1.0000x reference)
//
#include <hip/hip_runtime.h>
#include <math.h>

// Problem constants
#define Bq 2
#define Sq 2048
#define Cq 768
#define Hq 12
#define Dq 64
#define KZ 2              // K-split factor in attention

typedef __bf16 bfv8 __attribute__((ext_vector_type(8)));
typedef float f32x4 __attribute__((ext_vector_type(4)));
#define MFMA16(a, b, c) __builtin_amdgcn_mfma_f32_16x16x32_bf16(a, b, c, 0, 0, 0)

static __device__ inline unsigned short bfbits(float x) {
    __bf16 b = (__bf16)x;
    return __builtin_bit_cast(unsigned short, b);
}
static __device__ inline float bf2f(unsigned short b) {
    return (float)__builtin_bit_cast(__bf16, b);
}
static __device__ inline unsigned short lobits(float x, unsigned short hb) {
    return bfbits(x - bf2f(hb));
}

// ---------------------------------------------------------------------------
// Kernel 0: RoPE cos/sin tables  [S][32] each, fp64-accurate
// ---------------------------------------------------------------------------
__global__ void freq_kernel(float* __restrict__ ctab, float* __restrict__ stab) {
    int idx = blockIdx.x * blockDim.x + threadIdx.x;   // 0..65535
    int s = idx >> 5;
    int i = idx & 31;
    double f = (double)s * exp(-(double)i * 0.28782313662425573); // ln(1e4)/32
    ctab[idx] = (float)cos(f);
    stab[idx] = (float)sin(f);
}

// ---------------------------------------------------------------------------
// Tiled fp32 NT GEMM: out[m][n] = sum_k A[m][k] * B[n][k],  K = 768
// 128x128 tile, BK=16, 256 threads, 8x8 micro-tile per thread.
// MODE 0: QKV + fused RoPE -> writes bf16 hi/lo splits q,k,v in [B,H,S,D]
// MODE 1: proj + bias -> fp32 [M][768] (= final output)
// ---------------------------------------------------------------------------
template <int MODE>
__global__ __launch_bounds__(256) void gemm_kernel(
    const float* __restrict__ A, const float* __restrict__ Bm,
    const float* __restrict__ ctab, const float* __restrict__ stab,
    unsigned short* __restrict__ qhb, unsigned short* __restrict__ qlb,
    unsigned short* __restrict__ khb, unsigned short* __restrict__ klb,
    unsigned short* __restrict__ vhb, unsigned short* __restrict__ vlb,
    float* __restrict__ out0, const float* __restrict__ bias)
{
    __shared__ float aT[16][132];   // aT[k][m]
    __shared__ float bT[16][132];   // bT[k][n]

    const int t  = threadIdx.x;
    const int tx = t & 15;          // 0..15 -> n
    const int ty = t >> 4;          // 0..15 -> m
    const int lrow = t >> 1;        // 0..127 (row of tile being loaded)
    const int kq   = (t & 1) * 8;   // 0 or 8

    const int mBase = blockIdx.y * 128;
    const int nBase = blockIdx.x * 128;

    const float* Ap = A  + (mBase + lrow) * Cq + kq;
    const float* Bp = Bm + (nBase + lrow) * Cq + kq;

    float acc[8][8] = {};

    for (int k0 = 0; k0 < Cq; k0 += 16) {
        float4 a0 = *(const float4*)(Ap + k0);
        float4 a1 = *(const float4*)(Ap + k0 + 4);
        float4 b0 = *(const float4*)(Bp + k0);
        float4 b1 = *(const float4*)(Bp + k0 + 4);
        __syncthreads();   // previous compute finished reading LDS
        aT[kq + 0][lrow] = a0.x; aT[kq + 1][lrow] = a0.y;
        aT[kq + 2][lrow] = a0.z; aT[kq + 3][lrow] = a0.w;
        aT[kq + 4][lrow] = a1.x; aT[kq + 5][lrow] = a1.y;
        aT[kq + 6][lrow] = a1.z; aT[kq + 7][lrow] = a1.w;
        bT[kq + 0][lrow] = b0.x; bT[kq + 1][lrow] = b0.y;
        bT[kq + 2][lrow] = b0.z; bT[kq + 3][lrow] = b0.w;
        bT[kq + 4][lrow] = b1.x; bT[kq + 5][lrow] = b1.y;
        bT[kq + 6][lrow] = b1.z; bT[kq + 7][lrow] = b1.w;
        __syncthreads();
        #pragma unroll
        for (int kk = 0; kk < 16; ++kk) {
            float ar[8], br[8];
            *(float4*)&ar[0] = *(const float4*)&aT[kk][ty * 4];
            *(float4*)&ar[4] = *(const float4*)&aT[kk][64 + ty * 4];
            *(float4*)&br[0] = *(const float4*)&bT[kk][tx * 4];
            *(float4*)&br[4] = *(const float4*)&bT[kk][64 + tx * 4];
            #pragma unroll
            for (int i = 0; i < 8; ++i)
                #pragma unroll
                for (int j = 0; j < 8; ++j)
                    acc[i][j] = fmaf(ar[i], br[j], acc[i][j]);
        }
    }

    if (MODE == 0) {
        const int which = nBase / Cq;   // 0=q 1=k 2=v (128 | 768 -> uniform)
        unsigned short* hp = (which == 0) ? qhb : (which == 1) ? khb : vhb;
        unsigned short* lp = (which == 0) ? qlb : (which == 1) ? klb : vlb;
        #pragma unroll
        for (int ig = 0; ig < 2; ++ig) {
            #pragma unroll
            for (int jg = 0; jg < 2; ++jg) {
                const int cbase = nBase + jg * 64 + tx * 4;
                const int rem   = cbase - which * Cq;
                const int h     = rem >> 6;
                const int dd    = rem & 63;           // aligned to 4
                #pragma unroll
                for (int i = 0; i < 4; ++i) {
                    const int rg = mBase + ig * 64 + ty * 4 + i;
                    const int bb = rg >> 11;
                    const int ss = rg & 2047;
                    float v0 = acc[ig * 4 + i][jg * 4 + 0];
                    float v1 = acc[ig * 4 + i][jg * 4 + 1];
                    float v2 = acc[ig * 4 + i][jg * 4 + 2];
                    float v3 = acc[ig * 4 + i][jg * 4 + 3];
                    float o0, o1, o2, o3;
                    if (which < 2) {
                        const int fi = ss * 32 + (dd >> 1);
                        float c0 = ctab[fi],     s0 = stab[fi];
                        float c1 = ctab[fi + 1], s1 = stab[fi + 1];
                        o0 = v0 * c0 - v1 * s0;  o1 = v1 * c0 + v0 * s0;
                        o2 = v2 * c1 - v3 * s1;  o3 = v3 * c1 + v2 * s1;
                    } else {
                        o0 = v0; o1 = v1; o2 = v2; o3 = v3;
                    }
                    unsigned short h0 = bfbits(o0), h1 = bfbits(o1),
                                   h2 = bfbits(o2), h3 = bfbits(o3);
                    unsigned short l0 = lobits(o0, h0), l1 = lobits(o1, h1),
                                   l2 = lobits(o2, h2), l3 = lobits(o3, h3);
                    const size_t oidx = ((size_t)(bb * Hq + h) * Sq + ss) * Dq + dd;
                    *(ushort4*)&hp[oidx] = make_ushort4(h0, h1, h2, h3);
                    *(ushort4*)&lp[oidx] = make_ushort4(l0, l1, l2, l3);
                }
            }
        }
    } else {
        #pragma unroll
        for (int ig = 0; ig < 2; ++ig) {
            #pragma unroll
            for (int jg = 0; jg < 2; ++jg) {
                const int cbase = nBase + jg * 64 + tx * 4;
                float4 bz = *(const float4*)&bias[cbase];
                #pragma unroll
                for (int i = 0; i < 4; ++i) {
                    const int rg = mBase + ig * 64 + ty * 4 + i;
                    float4 r = make_float4(acc[ig*4+i][jg*4+0] + bz.x,
                                           acc[ig*4+i][jg*4+1] + bz.y,
                                           acc[ig*4+i][jg*4+2] + bz.z,
                                           acc[ig*4+i][jg*4+3] + bz.w);
                    *(float4*)&out0[(size_t)rg * Cq + cbase] = r;
                }
            }
        }
    }
}

// ---------------------------------------------------------------------------
// Kernel 1b: V transpose [B,H,S,D] -> [B,H,D,S], hi+lo packed through LDS.
// ---------------------------------------------------------------------------
__global__ __launch_bounds__(256) void vtrans_kernel(
    const unsigned short* __restrict__ vhb, const unsigned short* __restrict__ vlb,
    unsigned short* __restrict__ vThb, unsigned short* __restrict__ vTlb)
{
    __shared__ unsigned int lds[64][68];   // lds[d][s], (lo<<16)|hi
    const int t  = threadIdx.x;
    const int st = blockIdx.x;             // s tile (0..31)
    const int bh = blockIdx.y;             // 0..23
    const int lr = t >> 2;                 // 0..63
    const int lc = (t & 3) * 16;

    const size_t ibase = ((size_t)bh * Sq + st * 64) * Dq;
    #pragma unroll
    for (int u = 0; u < 16; u += 8) {
        unsigned short hv[8], lv[8];
        *(uint4*)hv = *(const uint4*)(vhb + ibase + (size_t)lr * Dq + lc + u);
        *(uint4*)lv = *(const uint4*)(vlb + ibase + (size_t)lr * Dq + lc + u);
        #pragma unroll
        for (int j = 0; j < 8; ++j)
            lds[lc + u + j][lr] = (unsigned)hv[j] | ((unsigned)lv[j] << 16);
    }
    __syncthreads();
    const int d  = t >> 2;
    const int sc = (t & 3) * 16;
    const size_t obase = ((size_t)bh * Dq + d) * Sq + st * 64 + sc;
    #pragma unroll
    for (int u = 0; u < 16; u += 8) {
        unsigned arr[8];
        *(uint4*)&arr[0] = *(const uint4*)&lds[d][sc + u];
        *(uint4*)&arr[4] = *(const uint4*)&lds[d][sc + u + 4];
        unsigned short h[8], l[8];
        #pragma unroll
        for (int j = 0; j < 8; ++j) {
            h[j] = (unsigned short)(arr[j] & 0xffffu);
            l[j] = (unsigned short)(arr[j] >> 16);
        }
        *(uint4*)(vThb + obase + u) = *(const uint4*)h;
        *(uint4*)(vTlb + obase + u) = *(const uint4*)l;
    }
}

// ---------------------------------------------------------------------------
// Kernel 2: MFMA flash attention, bf16 3-term split, K-split by KZ.
// 1D grid, XCD-swizzled: bi = n*24 + bh  =>  XCD(bi)=bi%8=bh%8, so each XCD
// owns heads {x, x+8, x+16}: 3 MB K/V working set fits the 4 MB per-XCD L2.
// ---------------------------------------------------------------------------
__global__ __launch_bounds__(256, 6) void attn_mfma_kernel(
    const unsigned short* __restrict__ qhb, const unsigned short* __restrict__ qlb,
    const unsigned short* __restrict__ khb, const unsigned short* __restrict__ klb,
    const unsigned short* __restrict__ vThb, const unsigned short* __restrict__ vTlb,
    float* __restrict__ Opart, float2* __restrict__ mlp)
{
    __shared__ unsigned int pbuf[4][16][68];   // per-wave P tile, (lo<<16)|hi

    const int t    = threadIdx.x;
    const int w    = t >> 6;
    const int lane = t & 63;
    const int ml   = lane & 15;
    const int quad = lane >> 4;
    const int bi   = blockIdx.x;            // 0..1535, bh-major for XCD affinity
    const int bh   = bi % 24;               // 0..23  -> XCD = bh % 8
    const int rest = bi / 24;               // 0..63
    const int qt   = rest >> 1;             // 0..31
    const int kz   = rest & 1;              // 0..KZ-1

    // ---- Q fragments (A-layout): row m=ml, k = ks*32 + quad*8 + j ----
    const size_t qoff = ((size_t)bh * Sq + qt * 64 + w * 16 + ml) * Dq + quad * 8;
    bfv8 aQh[2], aQl[2];
    #pragma unroll
    for (int ks = 0; ks < 2; ++ks) {
        aQh[ks] = *(const bfv8*)(qhb + qoff + ks * 32);
        aQl[ks] = *(const bfv8*)(qlb + qoff + ks * 32);
    }

    float m_st[4], l_st[4];
    f32x4 O[4];
    #pragma unroll
    for (int r = 0; r < 4; ++r) { m_st[r] = -INFINITY; l_st[r] = 0.f; }
    #pragma unroll
    for (int ng = 0; ng < 4; ++ng) O[ng] = (f32x4){0.f, 0.f, 0.f, 0.f};

    const int ktBeg = kz * (32 / KZ);
    const int ktEnd = ktBeg + (32 / KZ);
    for (int kt = ktBeg; kt < ktEnd; ++kt) {
        // ---- scores S = Q K^T : B-frag n = key, k = d ----
        f32x4 S[4];
        const size_t kbase = ((size_t)bh * Sq + kt * 64) * Dq + quad * 8;
        #pragma unroll
        for (int ng = 0; ng < 4; ++ng) {
            f32x4 acc = (f32x4){0.f, 0.f, 0.f, 0.f};
            #pragma unroll
            for (int ks = 0; ks < 2; ++ks) {
                const size_t ko = kbase + (size_t)(ng * 16 + ml) * Dq + ks * 32;
                bfv8 bKh = *(const bfv8*)(khb + ko);
                bfv8 bKl = *(const bfv8*)(klb + ko);
                acc = MFMA16(aQh[ks], bKh, acc);
                acc = MFMA16(aQl[ks], bKh, acc);
                acc = MFMA16(aQh[ks], bKl, acc);
            }
            S[ng] = acc;
        }

        // ---- online softmax (rows = quad*4 + r, cols across 16 lanes) ----
        float nm[4], alpha[4];
        #pragma unroll
        for (int r = 0; r < 4; ++r) {
            float mx = fmaxf(fmaxf(S[0][r], S[1][r]), fmaxf(S[2][r], S[3][r])) * 0.125f;
            #pragma unroll
            for (int off = 1; off < 16; off <<= 1)
                mx = fmaxf(mx, __shfl_xor(mx, off, 64));
            nm[r] = fmaxf(m_st[r], mx);
            alpha[r] = __expf(m_st[r] - nm[r]);
            m_st[r] = nm[r];
        }
        float ps[4] = {0.f, 0.f, 0.f, 0.f};
        #pragma unroll
        for (int ng = 0; ng < 4; ++ng) {
            #pragma unroll
            for (int r = 0; r < 4; ++r) {
                float p = __expf(S[ng][r] * 0.125f - nm[r]);
                ps[r] += p;
                unsigned short ph = bfbits(p);
                unsigned short pl = lobits(p, ph);
                pbuf[w][quad * 4 + r][ng * 16 + ml] =
                    (unsigned int)ph | ((unsigned int)pl << 16);
            }
        }
        #pragma unroll
        for (int r = 0; r < 4; ++r) {
            #pragma unroll
            for (int off = 1; off < 16; off <<= 1)
                ps[r] += __shfl_xor(ps[r], off, 64);
            l_st[r] = l_st[r] * alpha[r] + ps[r];
            O[0][r] *= alpha[r]; O[1][r] *= alpha[r];
            O[2][r] *= alpha[r]; O[3][r] *= alpha[r];
        }

        // ---- read P back as A-frags (wave-private LDS, DS pipe in-order) ----
        bfv8 aPh[2], aPl[2];
        #pragma unroll
        for (int ks = 0; ks < 2; ++ks) {
            const unsigned int* src = &pbuf[w][ml][ks * 32 + quad * 8];
            uint4 w0 = *(const uint4*)src;
            uint4 w1 = *(const uint4*)(src + 4);
            union { unsigned short s[8]; bfv8 v; } hu, lu;
            unsigned int arr[8] = {w0.x, w0.y, w0.z, w0.w, w1.x, w1.y, w1.z, w1.w};
            #pragma unroll
            for (int j = 0; j < 8; ++j) {
                hu.s[j] = (unsigned short)(arr[j] & 0xffffu);
                lu.s[j] = (unsigned short)(arr[j] >> 16);
            }
            aPh[ks] = hu.v;
            aPl[ks] = lu.v;
        }

        // ---- O += P V : B-frag n = d (vT[d][key]), k = key ----
        const size_t vbase = (size_t)bh * Dq * Sq + kt * 64 + quad * 8;
        #pragma unroll
        for (int ng = 0; ng < 4; ++ng) {
            #pragma unroll
            for (int ks = 0; ks < 2; ++ks) {
                const size_t vo = vbase + (size_t)(ng * 16 + ml) * Sq + ks * 32;
                bfv8 bVh = *(const bfv8*)(vThb + vo);
                bfv8 bVl = *(const bfv8*)(vTlb + vo);
                O[ng] = MFMA16(aPh[ks], bVh, O[ng]);
                O[ng] = MFMA16(aPl[ks], bVh, O[ng]);
                O[ng] = MFMA16(aPh[ks], bVl, O[ng]);
            }
        }
    }

    // ---- epilogue: write unnormalized partial O + (m,l) ----
    const size_t PART = (size_t)Bq * Hq * Sq * Dq;
    float* Op = Opart + PART * kz;
    #pragma unroll
    for (int r = 0; r < 4; ++r) {
        const int srow = qt * 64 + w * 16 + quad * 4 + r;
        const size_t row = (size_t)bh * Sq + srow;
        #pragma unroll
        for (int ng = 0; ng < 4; ++ng)
            Op[row * Dq + ng * 16 + ml] = O[ng][r];
        if (ml == 0)
            mlp[(size_t)kz * Bq * Hq * Sq + row] = make_float2(m_st[r], l_st[r]);
    }
}

// ---------------------------------------------------------------------------
// Kernel 3: combine KZ partial (O, m, l) -> attn [B,S,C] fp32
// ---------------------------------------------------------------------------
__global__ __launch_bounds__(256) void combine_kernel(
    const float* __restrict__ Opart, const float2* __restrict__ mlp,
    float* __restrict__ attn)
{
    const int idx = blockIdx.x * blockDim.x + threadIdx.x;  // BHSD/4 threads
    const int d4 = idx & 15;
    const int s  = (idx >> 4) & (Sq - 1);
    const int bh = idx >> 15;
    const size_t row  = (size_t)bh * Sq + s;
    const size_t PART = (size_t)Bq * Hq * Sq * Dq;
    const size_t MLP  = (size_t)Bq * Hq * Sq;

    float2 ml0 = mlp[row];
    float m = ml0.x;
    #pragma unroll
    for (int z = 1; z < KZ; ++z) m = fmaxf(m, mlp[z * MLP + row].x);

    float4 acc = make_float4(0.f, 0.f, 0.f, 0.f);
    float l = 0.f;
    #pragma unroll
    for (int z = 0; z < KZ; ++z) {
        float2 mlz = mlp[z * MLP + row];
        float wz = __expf(mlz.x - m);
        float4 Oz = *(const float4*)(Opart + z * PART + row * Dq + d4 * 4);
        acc.x += Oz.x * wz; acc.y += Oz.y * wz;
        acc.z += Oz.z * wz; acc.w += Oz.w * wz;
        l += mlz.y * wz;
    }
    const float il = 1.0f / l;
    const int bb = bh / Hq, hh = bh % Hq;
    float4 r = make_float4(acc.x * il, acc.y * il, acc.z * il, acc.w * il);
    *(float4*)&attn[((size_t)(bb * Sq + s)) * Cq + hh * Dq + d4 * 4] = r;
}

// ---------------------------------------------------------------------------
extern "C" void kernel_launch(void* const* d_in, const int* in_sizes, int n_in,
                              void* d_out, int out_size, void* d_ws, size_t ws_size,
                              hipStream_t stream) {
    const float* x     = (const float*)d_in[0];
    const float* Wqkv  = (const float*)d_in[1];
    const float* Wproj = (const float*)d_in[2];
    const float* bproj = (const float*)d_in[3];
    float* out = (float*)d_out;

    const size_t BHSD = (size_t)Bq * Hq * Sq * Dq;   // 3,145,728
    char* p = (char*)d_ws;
    unsigned short* qhb  = (unsigned short*)p; p += BHSD * 2;
    unsigned short* qlb  = (unsigned short*)p; p += BHSD * 2;
    unsigned short* khb  = (unsigned short*)p; p += BHSD * 2;
    unsigned short* klb  = (unsigned short*)p; p += BHSD * 2;
    unsigned short* vhb  = (unsigned short*)p; p += BHSD * 2;
    unsigned short* vlb  = (unsigned short*)p; p += BHSD * 2;
    unsigned short* vThb = (unsigned short*)p; p += BHSD * 2;
    unsigned short* vTlb = (unsigned short*)p; p += BHSD * 2;
    float*  attn  = (float*)p;  p += BHSD * 4;
    float*  Opart = (float*)p;  p += (size_t)KZ * BHSD * 4;
    float2* mlp   = (float2*)p; p += (size_t)KZ * Bq * Hq * Sq * 8;
    float*  ctab  = (float*)p;  p += (size_t)Sq * 32 * 4;
    float*  stab  = (float*)p;  p += (size_t)Sq * 32 * 4;
    // total ws use ~90 MB

    freq_kernel<<<256, 256, 0, stream>>>(ctab, stab);
    gemm_kernel<0><<<dim3(18, 32), 256, 0, stream>>>(
        x, Wqkv, ctab, stab, qhb, qlb, khb, klb, vhb, vlb, nullptr, nullptr);
    vtrans_kernel<<<dim3(32, 24), 256, 0, stream>>>(vhb, vlb, vThb, vTlb);
    attn_mfma_kernel<<<dim3(32 * 24 * KZ), 256, 0, stream>>>(
        qhb, qlb, khb, klb, vThb, vTlb, Opart, mlp);
    combine_kernel<<<(int)(BHSD / 4 / 256), 256, 0, stream>>>(Opart, mlp, attn);
    gemm_kernel<1><<<dim3(6, 32), 256, 0, stream>>>(
        attn, Wproj, ctab, stab, nullptr, nullptr, nullptr, nullptr, nullptr, nullptr,
        out, bproj);
}

// Round 6
// 648.534 us; speedup vs baseline: 1.2577x; 1.2577x over previous
//
#include <hip/hip_runtime.h>
#include <math.h>

// Problem constants
#define Bq 2
#define Sq 2048
#define Cq 768
#define Hq 12
#define Dq 64

typedef __bf16 bfv8 __attribute__((ext_vector_type(8)));
typedef float f32x4 __attribute__((ext_vector_type(4)));
#define MFMA16(a, b, c) __builtin_amdgcn_mfma_f32_16x16x32_bf16(a, b, c, 0, 0, 0)

static __device__ inline unsigned short bfbits(float x) {
    __bf16 b = (__bf16)x;
    return __builtin_bit_cast(unsigned short, b);
}
static __device__ inline float bf2f(unsigned short b) {
    return (float)__builtin_bit_cast(__bf16, b);
}
static __device__ inline unsigned short lobits(float x, unsigned short hb) {
    return bfbits(x - bf2f(hb));
}

// ---------------------------------------------------------------------------
// Kernel 0: RoPE cos/sin tables  [S][32] each, fp64-accurate
// ---------------------------------------------------------------------------
__global__ void freq_kernel(float* __restrict__ ctab, float* __restrict__ stab) {
    int idx = blockIdx.x * blockDim.x + threadIdx.x;   // 0..65535
    int s = idx >> 5;
    int i = idx & 31;
    double f = (double)s * exp(-(double)i * 0.28782313662425573); // ln(1e4)/32
    ctab[idx] = (float)cos(f);
    stab[idx] = (float)sin(f);
}

// ---------------------------------------------------------------------------
// Tiled fp32 NT GEMM: out[m][n] = sum_k A[m][k] * B[n][k],  K = 768
// MODE 0: QKV + fused RoPE -> bf16 hi/lo splits q,k,v in [B,H,S,D]
//         (q pre-scaled by 1/8 so attention skips the softmax scale)
// MODE 1: proj + bias -> fp32 [M][768] (= final output)
// ---------------------------------------------------------------------------
template <int MODE>
__global__ __launch_bounds__(256) void gemm_kernel(
    const float* __restrict__ A, const float* __restrict__ Bm,
    const float* __restrict__ ctab, const float* __restrict__ stab,
    unsigned short* __restrict__ qhb, unsigned short* __restrict__ qlb,
    unsigned short* __restrict__ khb, unsigned short* __restrict__ klb,
    unsigned short* __restrict__ vhb, unsigned short* __restrict__ vlb,
    float* __restrict__ out0, const float* __restrict__ bias)
{
    __shared__ float aT[16][132];   // aT[k][m]
    __shared__ float bT[16][132];   // bT[k][n]

    const int t  = threadIdx.x;
    const int tx = t & 15;          // 0..15 -> n
    const int ty = t >> 4;          // 0..15 -> m
    const int lrow = t >> 1;        // 0..127 (row of tile being loaded)
    const int kq   = (t & 1) * 8;   // 0 or 8

    const int mBase = blockIdx.y * 128;
    const int nBase = blockIdx.x * 128;

    const float* Ap = A  + (mBase + lrow) * Cq + kq;
    const float* Bp = Bm + (nBase + lrow) * Cq + kq;

    float acc[8][8] = {};

    for (int k0 = 0; k0 < Cq; k0 += 16) {
        float4 a0 = *(const float4*)(Ap + k0);
        float4 a1 = *(const float4*)(Ap + k0 + 4);
        float4 b0 = *(const float4*)(Bp + k0);
        float4 b1 = *(const float4*)(Bp + k0 + 4);
        __syncthreads();   // previous compute finished reading LDS
        aT[kq + 0][lrow] = a0.x; aT[kq + 1][lrow] = a0.y;
        aT[kq + 2][lrow] = a0.z; aT[kq + 3][lrow] = a0.w;
        aT[kq + 4][lrow] = a1.x; aT[kq + 5][lrow] = a1.y;
        aT[kq + 6][lrow] = a1.z; aT[kq + 7][lrow] = a1.w;
        bT[kq + 0][lrow] = b0.x; bT[kq + 1][lrow] = b0.y;
        bT[kq + 2][lrow] = b0.z; bT[kq + 3][lrow] = b0.w;
        bT[kq + 4][lrow] = b1.x; bT[kq + 5][lrow] = b1.y;
        bT[kq + 6][lrow] = b1.z; bT[kq + 7][lrow] = b1.w;
        __syncthreads();
        #pragma unroll
        for (int kk = 0; kk < 16; ++kk) {
            float ar[8], br[8];
            *(float4*)&ar[0] = *(const float4*)&aT[kk][ty * 4];
            *(float4*)&ar[4] = *(const float4*)&aT[kk][64 + ty * 4];
            *(float4*)&br[0] = *(const float4*)&bT[kk][tx * 4];
            *(float4*)&br[4] = *(const float4*)&bT[kk][64 + tx * 4];
            #pragma unroll
            for (int i = 0; i < 8; ++i)
                #pragma unroll
                for (int j = 0; j < 8; ++j)
                    acc[i][j] = fmaf(ar[i], br[j], acc[i][j]);
        }
    }

    if (MODE == 0) {
        const int which = nBase / Cq;   // 0=q 1=k 2=v (128 | 768 -> uniform)
        unsigned short* hp = (which == 0) ? qhb : (which == 1) ? khb : vhb;
        unsigned short* lp = (which == 0) ? qlb : (which == 1) ? klb : vlb;
        #pragma unroll
        for (int ig = 0; ig < 2; ++ig) {
            #pragma unroll
            for (int jg = 0; jg < 2; ++jg) {
                const int cbase = nBase + jg * 64 + tx * 4;
                const int rem   = cbase - which * Cq;
                const int h     = rem >> 6;
                const int dd    = rem & 63;           // aligned to 4
                #pragma unroll
                for (int i = 0; i < 4; ++i) {
                    const int rg = mBase + ig * 64 + ty * 4 + i;
                    const int bb = rg >> 11;
                    const int ss = rg & 2047;
                    float v0 = acc[ig * 4 + i][jg * 4 + 0];
                    float v1 = acc[ig * 4 + i][jg * 4 + 1];
                    float v2 = acc[ig * 4 + i][jg * 4 + 2];
                    float v3 = acc[ig * 4 + i][jg * 4 + 3];
                    float o0, o1, o2, o3;
                    if (which < 2) {
                        const int fi = ss * 32 + (dd >> 1);
                        float c0 = ctab[fi],     s0 = stab[fi];
                        float c1 = ctab[fi + 1], s1 = stab[fi + 1];
                        o0 = v0 * c0 - v1 * s0;  o1 = v1 * c0 + v0 * s0;
                        o2 = v2 * c1 - v3 * s1;  o3 = v3 * c1 + v2 * s1;
                        if (which == 0) {  // fold 64^-0.5 into q
                            o0 *= 0.125f; o1 *= 0.125f; o2 *= 0.125f; o3 *= 0.125f;
                        }
                    } else {
                        o0 = v0; o1 = v1; o2 = v2; o3 = v3;
                    }
                    unsigned short h0 = bfbits(o0), h1 = bfbits(o1),
                                   h2 = bfbits(o2), h3 = bfbits(o3);
                    unsigned short l0 = lobits(o0, h0), l1 = lobits(o1, h1),
                                   l2 = lobits(o2, h2), l3 = lobits(o3, h3);
                    const size_t oidx = ((size_t)(bb * Hq + h) * Sq + ss) * Dq + dd;
                    *(ushort4*)&hp[oidx] = make_ushort4(h0, h1, h2, h3);
                    *(ushort4*)&lp[oidx] = make_ushort4(l0, l1, l2, l3);
                }
            }
        }
    } else {
        #pragma unroll
        for (int ig = 0; ig < 2; ++ig) {
            #pragma unroll
            for (int jg = 0; jg < 2; ++jg) {
                const int cbase = nBase + jg * 64 + tx * 4;
                float4 bz = *(const float4*)&bias[cbase];
                #pragma unroll
                for (int i = 0; i < 4; ++i) {
                    const int rg = mBase + ig * 64 + ty * 4 + i;
                    float4 r = make_float4(acc[ig*4+i][jg*4+0] + bz.x,
                                           acc[ig*4+i][jg*4+1] + bz.y,
                                           acc[ig*4+i][jg*4+2] + bz.z,
                                           acc[ig*4+i][jg*4+3] + bz.w);
                    *(float4*)&out0[(size_t)rg * Cq + cbase] = r;
                }
            }
        }
    }
}

// ---------------------------------------------------------------------------
// Kernel 1b: V transpose [B,H,S,D] -> [B,H,D,S], hi+lo packed through LDS.
// ---------------------------------------------------------------------------
__global__ __launch_bounds__(256) void vtrans_kernel(
    const unsigned short* __restrict__ vhb, const unsigned short* __restrict__ vlb,
    unsigned short* __restrict__ vThb, unsigned short* __restrict__ vTlb)
{
    __shared__ unsigned int lds[64][68];   // lds[d][s], (lo<<16)|hi
    const int t  = threadIdx.x;
    const int st = blockIdx.x;             // s tile (0..31)
    const int bh = blockIdx.y;             // 0..23
    const int lr = t >> 2;                 // 0..63
    const int lc = (t & 3) * 16;

    const size_t ibase = ((size_t)bh * Sq + st * 64) * Dq;
    #pragma unroll
    for (int u = 0; u < 16; u += 8) {
        unsigned short hv[8], lv[8];
        *(uint4*)hv = *(const uint4*)(vhb + ibase + (size_t)lr * Dq + lc + u);
        *(uint4*)lv = *(const uint4*)(vlb + ibase + (size_t)lr * Dq + lc + u);
        #pragma unroll
        for (int j = 0; j < 8; ++j)
            lds[lc + u + j][lr] = (unsigned)hv[j] | ((unsigned)lv[j] << 16);
    }
    __syncthreads();
    const int d  = t >> 2;
    const int sc = (t & 3) * 16;
    const size_t obase = ((size_t)bh * Dq + d) * Sq + st * 64 + sc;
    #pragma unroll
    for (int u = 0; u < 16; u += 8) {
        unsigned arr[8];
        *(uint4*)&arr[0] = *(const uint4*)&lds[d][sc + u];
        *(uint4*)&arr[4] = *(const uint4*)&lds[d][sc + u + 4];
        unsigned short h[8], l[8];
        #pragma unroll
        for (int j = 0; j < 8; ++j) {
            h[j] = (unsigned short)(arr[j] & 0xffffu);
            l[j] = (unsigned short)(arr[j] >> 16);
        }
        *(uint4*)(vThb + obase + u) = *(const uint4*)h;
        *(uint4*)(vTlb + obase + u) = *(const uint4*)l;
    }
}

// ---------------------------------------------------------------------------
// Kernel 2: MFMA flash attention, bf16 3-term split.
// Grid 768 = 32 qt x 24 bh, bi = qt*24 + bh (XCD = bh%8, per-XCD K/V locality).
// K/V tile (64 keys) staged in LDS, shared by all 4 waves; register prefetch
// one tile ahead overlaps global latency with compute. Wave w stages array w.
// P C->A transform through small wave-private LDS in two key-half passes.
// 46 KB LDS -> 3 blocks/CU.
// ---------------------------------------------------------------------------
__global__ __launch_bounds__(256, 3) void attn_mfma_kernel(
    const unsigned short* __restrict__ qhb, const unsigned short* __restrict__ qlb,
    const unsigned short* __restrict__ khb, const unsigned short* __restrict__ klb,
    const unsigned short* __restrict__ vThb, const unsigned short* __restrict__ vTlb,
    float* __restrict__ attn)
{
    __shared__ unsigned short kh_s[64][72];   // [key][d]
    __shared__ unsigned short kl_s[64][72];
    __shared__ unsigned short vh_s[64][72];   // [d][key]
    __shared__ unsigned short vl_s[64][72];
    __shared__ unsigned int   pbuf[4][16][36]; // per-wave P half-tile, (lo<<16)|hi

    const int t    = threadIdx.x;
    const int w    = t >> 6;
    const int lane = t & 63;
    const int ml   = lane & 15;
    const int quad = lane >> 4;
    const int bi   = blockIdx.x;
    const int bh   = bi % 24;               // XCD = bh % 8
    const int qt   = bi / 24;               // 0..31

    // staging role: wave w loads array w
    const unsigned short* gsrc = (w == 0) ? khb : (w == 1) ? klb
                                : (w == 2) ? vThb : vTlb;
    unsigned short (*ldst)[72] = (w == 0) ? kh_s : (w == 1) ? kl_s
                                : (w == 2) ? vh_s : vl_s;
    const bool isV = (w >= 2);
    const size_t gbase = (size_t)bh * Sq * Dq;   // per-head base (K and V^T alike)

    // ---- Q fragments (A-layout): row m=ml, k = ks*32 + quad*8 + j ----
    const size_t qoff = ((size_t)bh * Sq + qt * 64 + w * 16 + ml) * Dq + quad * 8;
    bfv8 aQh[2], aQl[2];
    #pragma unroll
    for (int ks = 0; ks < 2; ++ks) {
        aQh[ks] = *(const bfv8*)(qhb + qoff + ks * 32);
        aQl[ks] = *(const bfv8*)(qlb + qoff + ks * 32);
    }

    float m_st[4], l_st[4];
    f32x4 O[4];
    #pragma unroll
    for (int r = 0; r < 4; ++r) { m_st[r] = -INFINITY; l_st[r] = 0.f; }
    #pragma unroll
    for (int ng = 0; ng < 4; ++ng) O[ng] = (f32x4){0.f, 0.f, 0.f, 0.f};

    // ---- prefetch tile 0 into registers ----
    uint4 pf[8];
    #pragma unroll
    for (int c = 0; c < 4; ++c)
        #pragma unroll
        for (int h2 = 0; h2 < 2; ++h2) {
            const int f = c * 1024 + lane * 16 + h2 * 8;
            const size_t g = isV ? gbase + (size_t)(f >> 6) * Sq + (f & 63)
                                 : gbase + f;
            pf[c * 2 + h2] = *(const uint4*)(gsrc + g);
        }

    for (int kt = 0; kt < 32; ++kt) {
        __syncthreads();               // all waves done reading previous tile
        #pragma unroll
        for (int c = 0; c < 4; ++c)
            #pragma unroll
            for (int h2 = 0; h2 < 2; ++h2) {
                const int row = c * 16 + (lane >> 2);
                const int col = (lane & 3) * 16 + h2 * 8;
                *(uint4*)&ldst[row][col] = pf[c * 2 + h2];
            }
        __syncthreads();
        if (kt + 1 < 32) {             // prefetch next tile (overlaps compute)
            #pragma unroll
            for (int c = 0; c < 4; ++c)
                #pragma unroll
                for (int h2 = 0; h2 < 2; ++h2) {
                    const int f = c * 1024 + lane * 16 + h2 * 8;
                    const size_t g = isV
                        ? gbase + (size_t)(f >> 6) * Sq + (kt + 1) * 64 + (f & 63)
                        : gbase + (size_t)(kt + 1) * 4096 + f;
                    pf[c * 2 + h2] = *(const uint4*)(gsrc + g);
                }
        }

        // ---- scores S = Q K^T (scale pre-folded into q) ----
        f32x4 S[4];
        #pragma unroll
        for (int ng = 0; ng < 4; ++ng) {
            f32x4 acc = (f32x4){0.f, 0.f, 0.f, 0.f};
            #pragma unroll
            for (int ks = 0; ks < 2; ++ks) {
                bfv8 bKh = *(const bfv8*)&kh_s[ng * 16 + ml][ks * 32 + quad * 8];
                bfv8 bKl = *(const bfv8*)&kl_s[ng * 16 + ml][ks * 32 + quad * 8];
                acc = MFMA16(aQh[ks], bKh, acc);
                acc = MFMA16(aQl[ks], bKh, acc);
                acc = MFMA16(aQh[ks], bKl, acc);
            }
            S[ng] = acc;
        }

        // ---- online softmax state update ----
        float nm[4], alpha[4];
        #pragma unroll
        for (int r = 0; r < 4; ++r) {
            float mx = fmaxf(fmaxf(S[0][r], S[1][r]), fmaxf(S[2][r], S[3][r]));
            #pragma unroll
            for (int off = 1; off < 16; off <<= 1)
                mx = fmaxf(mx, __shfl_xor(mx, off, 64));
            nm[r] = fmaxf(m_st[r], mx);
            alpha[r] = __expf(m_st[r] - nm[r]);
            m_st[r] = nm[r];
            O[0][r] *= alpha[r]; O[1][r] *= alpha[r];
            O[2][r] *= alpha[r]; O[3][r] *= alpha[r];
        }

        // ---- two key-half passes: exp -> pbuf -> A-frag -> PV ----
        float ps[4] = {0.f, 0.f, 0.f, 0.f};
        #pragma unroll
        for (int ksP = 0; ksP < 2; ++ksP) {
            #pragma unroll
            for (int g2 = 0; g2 < 2; ++g2) {
                const int ng = ksP * 2 + g2;
                #pragma unroll
                for (int r = 0; r < 4; ++r) {
                    float p = __expf(S[ng][r] - nm[r]);
                    ps[r] += p;
                    unsigned short ph = bfbits(p);
                    unsigned short pl = lobits(p, ph);
                    pbuf[w][quad * 4 + r][g2 * 16 + ml] =
                        (unsigned int)ph | ((unsigned int)pl << 16);
                }
            }
            // read back as A-frag (wave-private, DS pipe in-order per wave)
            bfv8 aPh, aPl;
            {
                const unsigned int* src = &pbuf[w][ml][quad * 8];
                uint4 w0 = *(const uint4*)src;
                uint4 w1 = *(const uint4*)(src + 4);
                union { unsigned short s[8]; bfv8 v; } hu, lu;
                unsigned int arr8[8] = {w0.x, w0.y, w0.z, w0.w,
                                        w1.x, w1.y, w1.z, w1.w};
                #pragma unroll
                for (int j = 0; j < 8; ++j) {
                    hu.s[j] = (unsigned short)(arr8[j] & 0xffffu);
                    lu.s[j] = (unsigned short)(arr8[j] >> 16);
                }
                aPh = hu.v;
                aPl = lu.v;
            }
            // O += P V for this key half (n = d groups)
            #pragma unroll
            for (int ngd = 0; ngd < 4; ++ngd) {
                bfv8 bVh = *(const bfv8*)&vh_s[ngd * 16 + ml][ksP * 32 + quad * 8];
                bfv8 bVl = *(const bfv8*)&vl_s[ngd * 16 + ml][ksP * 32 + quad * 8];
                O[ngd] = MFMA16(aPh, bVh, O[ngd]);
                O[ngd] = MFMA16(aPl, bVh, O[ngd]);
                O[ngd] = MFMA16(aPh, bVl, O[ngd]);
            }
        }
        #pragma unroll
        for (int r = 0; r < 4; ++r) {
            #pragma unroll
            for (int off = 1; off < 16; off <<= 1)
                ps[r] += __shfl_xor(ps[r], off, 64);
            l_st[r] = l_st[r] * alpha[r] + ps[r];
        }
    }

    // ---- epilogue: O /= l, write [B,S,C] fp32 ----
    const int bb = bh / Hq, hh = bh % Hq;
    #pragma unroll
    for (int r = 0; r < 4; ++r) {
        const float il = 1.0f / l_st[r];
        const int srow = qt * 64 + w * 16 + quad * 4 + r;
        const size_t obase = ((size_t)bb * Sq + srow) * Cq + hh * 64 + ml;
        #pragma unroll
        for (int ng = 0; ng < 4; ++ng)
            attn[obase + ng * 16] = O[ng][r] * il;
    }
}

// ---------------------------------------------------------------------------
extern "C" void kernel_launch(void* const* d_in, const int* in_sizes, int n_in,
                              void* d_out, int out_size, void* d_ws, size_t ws_size,
                              hipStream_t stream) {
    const float* x     = (const float*)d_in[0];
    const float* Wqkv  = (const float*)d_in[1];
    const float* Wproj = (const float*)d_in[2];
    const float* bproj = (const float*)d_in[3];
    float* out = (float*)d_out;

    const size_t BHSD = (size_t)Bq * Hq * Sq * Dq;   // 3,145,728
    char* p = (char*)d_ws;
    unsigned short* qhb  = (unsigned short*)p; p += BHSD * 2;
    unsigned short* qlb  = (unsigned short*)p; p += BHSD * 2;
    unsigned short* khb  = (unsigned short*)p; p += BHSD * 2;
    unsigned short* klb  = (unsigned short*)p; p += BHSD * 2;
    unsigned short* vhb  = (unsigned short*)p; p += BHSD * 2;
    unsigned short* vlb  = (unsigned short*)p; p += BHSD * 2;
    unsigned short* vThb = (unsigned short*)p; p += BHSD * 2;
    unsigned short* vTlb = (unsigned short*)p; p += BHSD * 2;
    float*  attn  = (float*)p;  p += BHSD * 4;
    float*  ctab  = (float*)p;  p += (size_t)Sq * 32 * 4;
    float*  stab  = (float*)p;  p += (size_t)Sq * 32 * 4;
    // total ws use ~63 MB

    freq_kernel<<<256, 256, 0, stream>>>(ctab, stab);
    gemm_kernel<0><<<dim3(18, 32), 256, 0, stream>>>(
        x, Wqkv, ctab, stab, qhb, qlb, khb, klb, vhb, vlb, nullptr, nullptr);
    vtrans_kernel<<<dim3(32, 24), 256, 0, stream>>>(vhb, vlb, vThb, vTlb);
    attn_mfma_kernel<<<dim3(32 * 24), 256, 0, stream>>>(
        qhb, qlb, khb, klb, vThb, vTlb, attn);
    gemm_kernel<1><<<dim3(6, 32), 256, 0, stream>>>(
        attn, Wproj, ctab, stab, nullptr, nullptr, nullptr, nullptr, nullptr, nullptr,
        out, bproj);
}

// Round 7
// 510.557 us; speedup vs baseline: 1.5976x; 1.2702x over previous
//
#include <hip/hip_runtime.h>
#include <math.h>

// Problem constants
#define Bq 2
#define Sq 2048
#define Cq 768
#define Hq 12
#define Dq 64

typedef __bf16 bfv8 __attribute__((ext_vector_type(8)));
typedef float f32x4 __attribute__((ext_vector_type(4)));
#define MFMA16(a, b, c) __builtin_amdgcn_mfma_f32_16x16x32_bf16(a, b, c, 0, 0, 0)

static __device__ inline unsigned short bfbits(float x) {
    __bf16 b = (__bf16)x;
    return __builtin_bit_cast(unsigned short, b);
}
static __device__ inline float bf2f(unsigned short b) {
    return (float)__builtin_bit_cast(__bf16, b);
}
static __device__ inline unsigned short lobits(float x, unsigned short hb) {
    return bfbits(x - bf2f(hb));
}

// async 16B global->LDS copy; lds dest must be wave-uniform base (+lane*16 HW)
static __device__ inline void gld_lds16(const unsigned short* g, unsigned short* l) {
    __builtin_amdgcn_global_load_lds(
        (const __attribute__((address_space(1))) unsigned int*)g,
        (__attribute__((address_space(3))) unsigned int*)l, 16, 0, 0);
}

// ---------------------------------------------------------------------------
// Kernel 0: RoPE cos/sin tables  [S][32] each, fp64-accurate
// ---------------------------------------------------------------------------
__global__ void freq_kernel(float* __restrict__ ctab, float* __restrict__ stab) {
    int idx = blockIdx.x * blockDim.x + threadIdx.x;   // 0..65535
    int s = idx >> 5;
    int i = idx & 31;
    double f = (double)s * exp(-(double)i * 0.28782313662425573); // ln(1e4)/32
    ctab[idx] = (float)cos(f);
    stab[idx] = (float)sin(f);
}

// ---------------------------------------------------------------------------
// Tiled fp32 NT GEMM: out[m][n] = sum_k A[m][k] * B[n][k],  K = 768
// MODE 0: QKV + fused RoPE -> bf16 hi/lo splits q,k,v in [B,H,S,D]
//         (q pre-scaled by 1/8 so attention skips the softmax scale)
// MODE 1: proj + bias -> fp32 [M][768] (= final output)
// ---------------------------------------------------------------------------
template <int MODE>
__global__ __launch_bounds__(256) void gemm_kernel(
    const float* __restrict__ A, const float* __restrict__ Bm,
    const float* __restrict__ ctab, const float* __restrict__ stab,
    unsigned short* __restrict__ qhb, unsigned short* __restrict__ qlb,
    unsigned short* __restrict__ khb, unsigned short* __restrict__ klb,
    unsigned short* __restrict__ vhb, unsigned short* __restrict__ vlb,
    float* __restrict__ out0, const float* __restrict__ bias)
{
    __shared__ float aT[16][132];   // aT[k][m]
    __shared__ float bT[16][132];   // bT[k][n]

    const int t  = threadIdx.x;
    const int tx = t & 15;          // 0..15 -> n
    const int ty = t >> 4;          // 0..15 -> m
    const int lrow = t >> 1;        // 0..127 (row of tile being loaded)
    const int kq   = (t & 1) * 8;   // 0 or 8

    const int mBase = blockIdx.y * 128;
    const int nBase = blockIdx.x * 128;

    const float* Ap = A  + (mBase + lrow) * Cq + kq;
    const float* Bp = Bm + (nBase + lrow) * Cq + kq;

    float acc[8][8] = {};

    for (int k0 = 0; k0 < Cq; k0 += 16) {
        float4 a0 = *(const float4*)(Ap + k0);
        float4 a1 = *(const float4*)(Ap + k0 + 4);
        float4 b0 = *(const float4*)(Bp + k0);
        float4 b1 = *(const float4*)(Bp + k0 + 4);
        __syncthreads();   // previous compute finished reading LDS
        aT[kq + 0][lrow] = a0.x; aT[kq + 1][lrow] = a0.y;
        aT[kq + 2][lrow] = a0.z; aT[kq + 3][lrow] = a0.w;
        aT[kq + 4][lrow] = a1.x; aT[kq + 5][lrow] = a1.y;
        aT[kq + 6][lrow] = a1.z; aT[kq + 7][lrow] = a1.w;
        bT[kq + 0][lrow] = b0.x; bT[kq + 1][lrow] = b0.y;
        bT[kq + 2][lrow] = b0.z; bT[kq + 3][lrow] = b0.w;
        bT[kq + 4][lrow] = b1.x; bT[kq + 5][lrow] = b1.y;
        bT[kq + 6][lrow] = b1.z; bT[kq + 7][lrow] = b1.w;
        __syncthreads();
        #pragma unroll
        for (int kk = 0; kk < 16; ++kk) {
            float ar[8], br[8];
            *(float4*)&ar[0] = *(const float4*)&aT[kk][ty * 4];
            *(float4*)&ar[4] = *(const float4*)&aT[kk][64 + ty * 4];
            *(float4*)&br[0] = *(const float4*)&bT[kk][tx * 4];
            *(float4*)&br[4] = *(const float4*)&bT[kk][64 + tx * 4];
            #pragma unroll
            for (int i = 0; i < 8; ++i)
                #pragma unroll
                for (int j = 0; j < 8; ++j)
                    acc[i][j] = fmaf(ar[i], br[j], acc[i][j]);
        }
    }

    if (MODE == 0) {
        const int which = nBase / Cq;   // 0=q 1=k 2=v (128 | 768 -> uniform)
        unsigned short* hp = (which == 0) ? qhb : (which == 1) ? khb : vhb;
        unsigned short* lp = (which == 0) ? qlb : (which == 1) ? klb : vlb;
        #pragma unroll
        for (int ig = 0; ig < 2; ++ig) {
            #pragma unroll
            for (int jg = 0; jg < 2; ++jg) {
                const int cbase = nBase + jg * 64 + tx * 4;
                const int rem   = cbase - which * Cq;
                const int h     = rem >> 6;
                const int dd    = rem & 63;           // aligned to 4
                #pragma unroll
                for (int i = 0; i < 4; ++i) {
                    const int rg = mBase + ig * 64 + ty * 4 + i;
                    const int bb = rg >> 11;
                    const int ss = rg & 2047;
                    float v0 = acc[ig * 4 + i][jg * 4 + 0];
                    float v1 = acc[ig * 4 + i][jg * 4 + 1];
                    float v2 = acc[ig * 4 + i][jg * 4 + 2];
                    float v3 = acc[ig * 4 + i][jg * 4 + 3];
                    float o0, o1, o2, o3;
                    if (which < 2) {
                        const int fi = ss * 32 + (dd >> 1);
                        float c0 = ctab[fi],     s0 = stab[fi];
                        float c1 = ctab[fi + 1], s1 = stab[fi + 1];
                        o0 = v0 * c0 - v1 * s0;  o1 = v1 * c0 + v0 * s0;
                        o2 = v2 * c1 - v3 * s1;  o3 = v3 * c1 + v2 * s1;
                        if (which == 0) {  // fold 64^-0.5 into q
                            o0 *= 0.125f; o1 *= 0.125f; o2 *= 0.125f; o3 *= 0.125f;
                        }
                    } else {
                        o0 = v0; o1 = v1; o2 = v2; o3 = v3;
                    }
                    unsigned short h0 = bfbits(o0), h1 = bfbits(o1),
                                   h2 = bfbits(o2), h3 = bfbits(o3);
                    unsigned short l0 = lobits(o0, h0), l1 = lobits(o1, h1),
                                   l2 = lobits(o2, h2), l3 = lobits(o3, h3);
                    const size_t oidx = ((size_t)(bb * Hq + h) * Sq + ss) * Dq + dd;
                    *(ushort4*)&hp[oidx] = make_ushort4(h0, h1, h2, h3);
                    *(ushort4*)&lp[oidx] = make_ushort4(l0, l1, l2, l3);
                }
            }
        }
    } else {
        #pragma unroll
        for (int ig = 0; ig < 2; ++ig) {
            #pragma unroll
            for (int jg = 0; jg < 2; ++jg) {
                const int cbase = nBase + jg * 64 + tx * 4;
                float4 bz = *(const float4*)&bias[cbase];
                #pragma unroll
                for (int i = 0; i < 4; ++i) {
                    const int rg = mBase + ig * 64 + ty * 4 + i;
                    float4 r = make_float4(acc[ig*4+i][jg*4+0] + bz.x,
                                           acc[ig*4+i][jg*4+1] + bz.y,
                                           acc[ig*4+i][jg*4+2] + bz.z,
                                           acc[ig*4+i][jg*4+3] + bz.w);
                    *(float4*)&out0[(size_t)rg * Cq + cbase] = r;
                }
            }
        }
    }
}

// ---------------------------------------------------------------------------
// Kernel 1b: V transpose [B,H,S,D] -> [B,H,D,S], hi+lo packed through LDS.
// ---------------------------------------------------------------------------
__global__ __launch_bounds__(256) void vtrans_kernel(
    const unsigned short* __restrict__ vhb, const unsigned short* __restrict__ vlb,
    unsigned short* __restrict__ vThb, unsigned short* __restrict__ vTlb)
{
    __shared__ unsigned int lds[64][68];   // lds[d][s], (lo<<16)|hi
    const int t  = threadIdx.x;
    const int st = blockIdx.x;             // s tile (0..31)
    const int bh = blockIdx.y;             // 0..23
    const int lr = t >> 2;                 // 0..63
    const int lc = (t & 3) * 16;

    const size_t ibase = ((size_t)bh * Sq + st * 64) * Dq;
    #pragma unroll
    for (int u = 0; u < 16; u += 8) {
        unsigned short hv[8], lv[8];
        *(uint4*)hv = *(const uint4*)(vhb + ibase + (size_t)lr * Dq + lc + u);
        *(uint4*)lv = *(const uint4*)(vlb + ibase + (size_t)lr * Dq + lc + u);
        #pragma unroll
        for (int j = 0; j < 8; ++j)
            lds[lc + u + j][lr] = (unsigned)hv[j] | ((unsigned)lv[j] << 16);
    }
    __syncthreads();
    const int d  = t >> 2;
    const int sc = (t & 3) * 16;
    const size_t obase = ((size_t)bh * Dq + d) * Sq + st * 64 + sc;
    #pragma unroll
    for (int u = 0; u < 16; u += 8) {
        unsigned arr[8];
        *(uint4*)&arr[0] = *(const uint4*)&lds[d][sc + u];
        *(uint4*)&arr[4] = *(const uint4*)&lds[d][sc + u + 4];
        unsigned short h[8], l[8];
        #pragma unroll
        for (int j = 0; j < 8; ++j) {
            h[j] = (unsigned short)(arr[j] & 0xffffu);
            l[j] = (unsigned short)(arr[j] >> 16);
        }
        *(uint4*)(vThb + obase + u) = *(const uint4*)h;
        *(uint4*)(vTlb + obase + u) = *(const uint4*)l;
    }
}

// ---------------------------------------------------------------------------
// Kernel 2: MFMA flash attention, bf16 3-term split.
// Grid 768 = 32 qt x 24 bh (XCD = bh%8 K/V locality). K/V tile staged via
// global_load_lds (async DMA, no VGPR round-trip, no spill) in the m97
// 2-barrier structure; DMA stalls overlap across the 3 resident blocks/CU.
// LDS tile layout XOR-swizzled at 16B granularity (swizzle applied on the
// per-lane GLOBAL address; LDS side is lane-linear as the DMA requires):
//   element (row, chunk cc) lives at physical chunk cc ^ (row & 7).
// 41 KB LDS -> 3 blocks/CU.
// ---------------------------------------------------------------------------
__global__ __launch_bounds__(256, 3) void attn_mfma_kernel(
    const unsigned short* __restrict__ qhb, const unsigned short* __restrict__ qlb,
    const unsigned short* __restrict__ khb, const unsigned short* __restrict__ klb,
    const unsigned short* __restrict__ vThb, const unsigned short* __restrict__ vTlb,
    float* __restrict__ attn)
{
    __shared__ unsigned short kv_s[4][4096];   // w=0:kh 1:kl 2:vh 3:vl
    __shared__ unsigned int   pbuf[4][16][36]; // per-wave P half-tile, (lo<<16)|hi

    const int t    = threadIdx.x;
    const int w    = t >> 6;
    const int lane = t & 63;
    const int ml   = lane & 15;
    const int quad = lane >> 4;
    const int bi   = blockIdx.x;
    const int bh   = bi % 24;               // XCD = bh % 8
    const int qt   = bi / 24;               // 0..31

    // staging role: wave w DMAs array w (K rows are [key][d], V rows [d][key])
    const unsigned short* gsrc = (w == 0) ? khb : (w == 1) ? klb
                                : (w == 2) ? vThb : vTlb;
    const bool isV = (w >= 2);
    const size_t gbase = (size_t)bh * Sq * Dq;   // per-head base

    // per-lane swizzled global offsets (shorts), one per 1KB DMA issue
    unsigned int goff[8];
    #pragma unroll
    for (int i = 0; i < 8; ++i) {
        const int prow = i * 8 + (lane >> 3);        // physical LDS row
        const int cc   = (lane & 7) ^ (prow & 7);    // logical 16B chunk
        goff[i] = isV ? (unsigned)(prow * Sq + cc * 8)
                      : (unsigned)(prow * 64 + cc * 8);
    }

    // ---- Q fragments (A-layout): row m=ml, k = ks*32 + quad*8 + j ----
    const size_t qoff = ((size_t)bh * Sq + qt * 64 + w * 16 + ml) * Dq + quad * 8;
    bfv8 aQh[2], aQl[2];
    #pragma unroll
    for (int ks = 0; ks < 2; ++ks) {
        aQh[ks] = *(const bfv8*)(qhb + qoff + ks * 32);
        aQl[ks] = *(const bfv8*)(qlb + qoff + ks * 32);
    }

    float m_st[4], l_st[4];
    f32x4 O[4];
    #pragma unroll
    for (int r = 0; r < 4; ++r) { m_st[r] = -INFINITY; l_st[r] = 0.f; }
    #pragma unroll
    for (int ng = 0; ng < 4; ++ng) O[ng] = (f32x4){0.f, 0.f, 0.f, 0.f};

    for (int kt = 0; kt < 32; ++kt) {
        __syncthreads();               // all waves done reading previous tile
        {
            const unsigned short* gt = gsrc + gbase + (isV ? kt * 64 : kt * 4096);
            #pragma unroll
            for (int i = 0; i < 8; ++i)
                gld_lds16(gt + goff[i], &kv_s[w][i * 512]);
        }
        __syncthreads();               // vmcnt drain before barrier -> tile ready

        // ---- scores S = Q K^T (scale pre-folded into q) ----
        f32x4 S[4];
        #pragma unroll
        for (int ng = 0; ng < 4; ++ng) {
            f32x4 acc = (f32x4){0.f, 0.f, 0.f, 0.f};
            #pragma unroll
            for (int ks = 0; ks < 2; ++ks) {
                const int rr = ng * 16 + ml;
                const int off = rr * 64 + ((((ks * 4 + quad) ^ (rr & 7))) << 3);
                bfv8 bKh = *(const bfv8*)&kv_s[0][off];
                bfv8 bKl = *(const bfv8*)&kv_s[1][off];
                acc = MFMA16(aQh[ks], bKh, acc);
                acc = MFMA16(aQl[ks], bKh, acc);
                acc = MFMA16(aQh[ks], bKl, acc);
            }
            S[ng] = acc;
        }

        // ---- online softmax state update ----
        float nm[4], alpha[4];
        #pragma unroll
        for (int r = 0; r < 4; ++r) {
            float mx = fmaxf(fmaxf(S[0][r], S[1][r]), fmaxf(S[2][r], S[3][r]));
            #pragma unroll
            for (int off = 1; off < 16; off <<= 1)
                mx = fmaxf(mx, __shfl_xor(mx, off, 64));
            nm[r] = fmaxf(m_st[r], mx);
            alpha[r] = __expf(m_st[r] - nm[r]);
            m_st[r] = nm[r];
            O[0][r] *= alpha[r]; O[1][r] *= alpha[r];
            O[2][r] *= alpha[r]; O[3][r] *= alpha[r];
        }

        // ---- two key-half passes: exp -> pbuf -> A-frag -> PV ----
        float ps[4] = {0.f, 0.f, 0.f, 0.f};
        #pragma unroll
        for (int ksP = 0; ksP < 2; ++ksP) {
            #pragma unroll
            for (int g2 = 0; g2 < 2; ++g2) {
                const int ng = ksP * 2 + g2;
                #pragma unroll
                for (int r = 0; r < 4; ++r) {
                    float p = __expf(S[ng][r] - nm[r]);
                    ps[r] += p;
                    unsigned short ph = bfbits(p);
                    unsigned short pl = lobits(p, ph);
                    pbuf[w][quad * 4 + r][g2 * 16 + ml] =
                        (unsigned int)ph | ((unsigned int)pl << 16);
                }
            }
            // read back as A-frag (wave-private, DS pipe in-order per wave)
            bfv8 aPh, aPl;
            {
                const unsigned int* src = &pbuf[w][ml][quad * 8];
                uint4 w0 = *(const uint4*)src;
                uint4 w1 = *(const uint4*)(src + 4);
                union { unsigned short s[8]; bfv8 v; } hu, lu;
                unsigned int arr8[8] = {w0.x, w0.y, w0.z, w0.w,
                                        w1.x, w1.y, w1.z, w1.w};
                #pragma unroll
                for (int j = 0; j < 8; ++j) {
                    hu.s[j] = (unsigned short)(arr8[j] & 0xffffu);
                    lu.s[j] = (unsigned short)(arr8[j] >> 16);
                }
                aPh = hu.v;
                aPl = lu.v;
            }
            // O += P V for this key half (n = d groups)
            #pragma unroll
            for (int ngd = 0; ngd < 4; ++ngd) {
                const int rr = ngd * 16 + ml;
                const int off = rr * 64 + ((((ksP * 4 + quad) ^ (rr & 7))) << 3);
                bfv8 bVh = *(const bfv8*)&kv_s[2][off];
                bfv8 bVl = *(const bfv8*)&kv_s[3][off];
                O[ngd] = MFMA16(aPh, bVh, O[ngd]);
                O[ngd] = MFMA16(aPl, bVh, O[ngd]);
                O[ngd] = MFMA16(aPh, bVl, O[ngd]);
            }
        }
        #pragma unroll
        for (int r = 0; r < 4; ++r) {
            #pragma unroll
            for (int off = 1; off < 16; off <<= 1)
                ps[r] += __shfl_xor(ps[r], off, 64);
            l_st[r] = l_st[r] * alpha[r] + ps[r];
        }
    }

    // ---- epilogue: O /= l, write [B,S,C] fp32 ----
    const int bb = bh / Hq, hh = bh % Hq;
    #pragma unroll
    for (int r = 0; r < 4; ++r) {
        const float il = 1.0f / l_st[r];
        const int srow = qt * 64 + w * 16 + quad * 4 + r;
        const size_t obase = ((size_t)bb * Sq + srow) * Cq + hh * 64 + ml;
        #pragma unroll
        for (int ng = 0; ng < 4; ++ng)
            attn[obase + ng * 16] = O[ng][r] * il;
    }
}

// ---------------------------------------------------------------------------
extern "C" void kernel_launch(void* const* d_in, const int* in_sizes, int n_in,
                              void* d_out, int out_size, void* d_ws, size_t ws_size,
                              hipStream_t stream) {
    const float* x     = (const float*)d_in[0];
    const float* Wqkv  = (const float*)d_in[1];
    const float* Wproj = (const float*)d_in[2];
    const float* bproj = (const float*)d_in[3];
    float* out = (float*)d_out;

    const size_t BHSD = (size_t)Bq * Hq * Sq * Dq;   // 3,145,728
    char* p = (char*)d_ws;
    unsigned short* qhb  = (unsigned short*)p; p += BHSD * 2;
    unsigned short* qlb  = (unsigned short*)p; p += BHSD * 2;
    unsigned short* khb  = (unsigned short*)p; p += BHSD * 2;
    unsigned short* klb  = (unsigned short*)p; p += BHSD * 2;
    unsigned short* vhb  = (unsigned short*)p; p += BHSD * 2;
    unsigned short* vlb  = (unsigned short*)p; p += BHSD * 2;
    unsigned short* vThb = (unsigned short*)p; p += BHSD * 2;
    unsigned short* vTlb = (unsigned short*)p; p += BHSD * 2;
    float*  attn  = (float*)p;  p += BHSD * 4;
    float*  ctab  = (float*)p;  p += (size_t)Sq * 32 * 4;
    float*  stab  = (float*)p;  p += (size_t)Sq * 32 * 4;
    // total ws use ~63 MB

    freq_kernel<<<256, 256, 0, stream>>>(ctab, stab);
    gemm_kernel<0><<<dim3(18, 32), 256, 0, stream>>>(
        x, Wqkv, ctab, stab, qhb, qlb, khb, klb, vhb, vlb, nullptr, nullptr);
    vtrans_kernel<<<dim3(32, 24), 256, 0, stream>>>(vhb, vlb, vThb, vTlb);
    attn_mfma_kernel<<<dim3(32 * 24), 256, 0, stream>>>(
        qhb, qlb, khb, klb, vThb, vTlb, attn);
    gemm_kernel<1><<<dim3(6, 32), 256, 0, stream>>>(
        attn, Wproj, ctab, stab, nullptr, nullptr, nullptr, nullptr, nullptr, nullptr,
        out, bproj);
}

// Round 8
// 323.110 us; speedup vs baseline: 2.5243x; 1.5801x over previous
//
#include <hip/hip_runtime.h>
#include <math.h>

// Problem constants
#define Bq 2
#define Sq 2048
#define Cq 768
#define Hq 12
#define Dq 64

typedef __bf16 bfv8 __attribute__((ext_vector_type(8)));
typedef float f32x4 __attribute__((ext_vector_type(4)));
#define MFMA16(a, b, c) __builtin_amdgcn_mfma_f32_16x16x32_bf16(a, b, c, 0, 0, 0)

static __device__ inline unsigned short bfbits(float x) {
    __bf16 b = (__bf16)x;
    return __builtin_bit_cast(unsigned short, b);
}
static __device__ inline float bf2f(unsigned short b) {
    return (float)__builtin_bit_cast(__bf16, b);
}
static __device__ inline unsigned short lobits(float x, unsigned short hb) {
    return bfbits(x - bf2f(hb));
}

// async 16B global->LDS copy; lds dest must be wave-uniform base (+lane*16 HW)
static __device__ inline void gld_lds16(const unsigned short* g, unsigned short* l) {
    __builtin_amdgcn_global_load_lds(
        (const __attribute__((address_space(1))) unsigned int*)g,
        (__attribute__((address_space(3))) unsigned int*)l, 16, 0, 0);
}

// ---------------------------------------------------------------------------
// Kernel 0: RoPE cos/sin tables  [S][32] each, fp64-accurate
// ---------------------------------------------------------------------------
__global__ void freq_kernel(float* __restrict__ ctab, float* __restrict__ stab) {
    int idx = blockIdx.x * blockDim.x + threadIdx.x;   // 0..65535
    int s = idx >> 5;
    int i = idx & 31;
    double f = (double)s * exp(-(double)i * 0.28782313662425573); // ln(1e4)/32
    ctab[idx] = (float)cos(f);
    stab[idx] = (float)sin(f);
}

// ---------------------------------------------------------------------------
// MFMA NT GEMM, fp32 in via bf16 3-term split: out[m][n] = sum_k A[m][k]B[n][k]
// 128x128 tile, BK=32 (one 16x16x32 MFMA k-step), 256 thr = 4 waves (2x2),
// 4x4 16x16 acc tiles per wave. fp32 global -> hi/lo bf16 at staging; padded
// LDS (stride 40 shorts = 80B, 16B aligned, balanced banks for ds_read_b128).
// MODE 0: QKV. Epilogue RoPE in C-layout (pair partner = ml^1 lane via
//         __shfl_xor), q pre-scaled 1/8; q,k hi/lo in [B,H,S,D]; V written
//         DIRECTLY TRANSPOSED [B,H,D,S] (C-layout r-values = consecutive s).
// MODE 1: proj + bias -> fp32 [M][768].
// ---------------------------------------------------------------------------
template <int MODE>
__global__ __launch_bounds__(256) void gemm_mfma_kernel(
    const float* __restrict__ A, const float* __restrict__ Bm,
    const float* __restrict__ ctab, const float* __restrict__ stab,
    unsigned short* __restrict__ qhb, unsigned short* __restrict__ qlb,
    unsigned short* __restrict__ khb, unsigned short* __restrict__ klb,
    unsigned short* __restrict__ vThb, unsigned short* __restrict__ vTlb,
    float* __restrict__ out0, const float* __restrict__ bias)
{
    __shared__ unsigned short aH[128][40], aL[128][40];
    __shared__ unsigned short bH[128][40], bL[128][40];

    const int t    = threadIdx.x;
    const int w    = t >> 6;
    const int lane = t & 63;
    const int ml   = lane & 15;
    const int quad = lane >> 4;
    const int wm   = w >> 1;         // wave m position (0..1)
    const int wn   = w & 1;          // wave n position (0..1)

    const int mBase = blockIdx.y * 128;
    const int nBase = blockIdx.x * 128;

    const int row = t >> 1;          // 0..127 staging row
    const int kq  = (t & 1) * 16;    // 0 or 16

    const float* Ap  = A  + (size_t)(mBase + row) * Cq + kq;
    const float* Bp2 = Bm + (size_t)(nBase + row) * Cq + kq;

    f32x4 acc[4][4];
    #pragma unroll
    for (int mi = 0; mi < 4; ++mi)
        #pragma unroll
        for (int ni = 0; ni < 4; ++ni)
            acc[mi][ni] = (f32x4){0.f, 0.f, 0.f, 0.f};

    for (int k0 = 0; k0 < Cq; k0 += 32) {
        float4 av[4], bv[4];
        #pragma unroll
        for (int c = 0; c < 4; ++c) {
            av[c] = *(const float4*)(Ap  + k0 + c * 4);
            bv[c] = *(const float4*)(Bp2 + k0 + c * 4);
        }
        __syncthreads();   // waves done reading LDS from previous iter
        {
            unsigned short ah[16], al[16], bh[16], bl[16];
            #pragma unroll
            for (int c = 0; c < 4; ++c) {
                const float* af = (const float*)&av[c];
                const float* bf = (const float*)&bv[c];
                #pragma unroll
                for (int j = 0; j < 4; ++j) {
                    unsigned short h0 = bfbits(af[j]);
                    ah[c * 4 + j] = h0;
                    al[c * 4 + j] = lobits(af[j], h0);
                    unsigned short h1 = bfbits(bf[j]);
                    bh[c * 4 + j] = h1;
                    bl[c * 4 + j] = lobits(bf[j], h1);
                }
            }
            *(uint4*)&aH[row][kq]     = *(uint4*)&ah[0];
            *(uint4*)&aH[row][kq + 8] = *(uint4*)&ah[8];
            *(uint4*)&aL[row][kq]     = *(uint4*)&al[0];
            *(uint4*)&aL[row][kq + 8] = *(uint4*)&al[8];
            *(uint4*)&bH[row][kq]     = *(uint4*)&bh[0];
            *(uint4*)&bH[row][kq + 8] = *(uint4*)&bh[8];
            *(uint4*)&bL[row][kq]     = *(uint4*)&bl[0];
            *(uint4*)&bL[row][kq + 8] = *(uint4*)&bl[8];
        }
        __syncthreads();

        bfv8 aFh[4], aFl[4], bFh[4], bFl[4];
        #pragma unroll
        for (int mi = 0; mi < 4; ++mi) {
            const int r = wm * 64 + mi * 16 + ml;
            aFh[mi] = *(const bfv8*)&aH[r][quad * 8];
            aFl[mi] = *(const bfv8*)&aL[r][quad * 8];
        }
        #pragma unroll
        for (int ni = 0; ni < 4; ++ni) {
            const int r = wn * 64 + ni * 16 + ml;
            bFh[ni] = *(const bfv8*)&bH[r][quad * 8];
            bFl[ni] = *(const bfv8*)&bL[r][quad * 8];
        }
        #pragma unroll
        for (int mi = 0; mi < 4; ++mi)
            #pragma unroll
            for (int ni = 0; ni < 4; ++ni) {
                acc[mi][ni] = MFMA16(aFh[mi], bFh[ni], acc[mi][ni]);
                acc[mi][ni] = MFMA16(aFl[mi], bFh[ni], acc[mi][ni]);
                acc[mi][ni] = MFMA16(aFh[mi], bFl[ni], acc[mi][ni]);
            }
    }

    // ---- epilogue (C-layout: row = quad*4 + r, col = ml) ----
    if (MODE == 0) {
        const int which = nBase / Cq;   // 0=q 1=k 2=v (128 | 768 -> uniform)
        #pragma unroll
        for (int mi = 0; mi < 4; ++mi) {
            const int gm = mBase + wm * 64 + mi * 16 + quad * 4;  // + r
            const int bb = gm >> 11;
            const int s0 = gm & 2047;          // rows gm..gm+3 same bb
            #pragma unroll
            for (int ni = 0; ni < 4; ++ni) {
                const int gn = nBase + wn * 64 + ni * 16 + ml;
                const int c  = gn - which * Cq;
                const int hh = c >> 6;
                const int dd = c & 63;
                if (which < 2) {
                    unsigned short* hp = (which == 0) ? qhb : khb;
                    unsigned short* lp = (which == 0) ? qlb : klb;
                    #pragma unroll
                    for (int r = 0; r < 4; ++r) {
                        float val = acc[mi][ni][r];
                        float pv  = __shfl_xor(val, 1, 64);   // d-pair partner
                        const int fi = (s0 + r) * 32 + (dd >> 1);
                        float c0 = ctab[fi], sn = stab[fi];
                        float o = (dd & 1) ? (val * c0 + pv * sn)
                                           : (val * c0 - pv * sn);
                        if (which == 0) o *= 0.125f;          // fold 64^-0.5
                        unsigned short h0 = bfbits(o);
                        const size_t oidx =
                            ((size_t)(bb * Hq + hh) * Sq + s0 + r) * Dq + dd;
                        hp[oidx] = h0;
                        lp[oidx] = lobits(o, h0);
                    }
                } else {
                    // V: write transposed [B,H,D,S]; r-values = consecutive s
                    unsigned short hv[4], lv[4];
                    #pragma unroll
                    for (int r = 0; r < 4; ++r) {
                        float o = acc[mi][ni][r];
                        hv[r] = bfbits(o);
                        lv[r] = lobits(o, hv[r]);
                    }
                    const size_t oT =
                        ((size_t)(bb * Hq + hh) * Dq + dd) * Sq + s0;
                    *(ushort4*)&vThb[oT] = *(ushort4*)hv;
                    *(ushort4*)&vTlb[oT] = *(ushort4*)lv;
                }
            }
        }
    } else {
        #pragma unroll
        for (int mi = 0; mi < 4; ++mi) {
            const int gm = mBase + wm * 64 + mi * 16 + quad * 4;
            #pragma unroll
            for (int ni = 0; ni < 4; ++ni) {
                const int gn = nBase + wn * 64 + ni * 16 + ml;
                const float bz = bias[gn];
                #pragma unroll
                for (int r = 0; r < 4; ++r)
                    out0[(size_t)(gm + r) * Cq + gn] = acc[mi][ni][r] + bz;
            }
        }
    }
}

// ---------------------------------------------------------------------------
// Kernel 2: MFMA flash attention, bf16 3-term split.
// Grid 768 = 32 qt x 24 bh (XCD = bh%8 K/V locality). K/V tile staged via
// global_load_lds; 16B XOR swizzle applied on per-lane GLOBAL address.
// ---------------------------------------------------------------------------
__global__ __launch_bounds__(256, 3) void attn_mfma_kernel(
    const unsigned short* __restrict__ qhb, const unsigned short* __restrict__ qlb,
    const unsigned short* __restrict__ khb, const unsigned short* __restrict__ klb,
    const unsigned short* __restrict__ vThb, const unsigned short* __restrict__ vTlb,
    float* __restrict__ attn)
{
    __shared__ unsigned short kv_s[4][4096];   // w=0:kh 1:kl 2:vh 3:vl
    __shared__ unsigned int   pbuf[4][16][36]; // per-wave P half-tile

    const int t    = threadIdx.x;
    const int w    = t >> 6;
    const int lane = t & 63;
    const int ml   = lane & 15;
    const int quad = lane >> 4;
    const int bi   = blockIdx.x;
    const int bh   = bi % 24;               // XCD = bh % 8
    const int qt   = bi / 24;               // 0..31

    const unsigned short* gsrc = (w == 0) ? khb : (w == 1) ? klb
                                : (w == 2) ? vThb : vTlb;
    const bool isV = (w >= 2);
    const size_t gbase = (size_t)bh * Sq * Dq;

    unsigned int goff[8];
    #pragma unroll
    for (int i = 0; i < 8; ++i) {
        const int prow = i * 8 + (lane >> 3);        // physical LDS row
        const int cc   = (lane & 7) ^ (prow & 7);    // logical 16B chunk
        goff[i] = isV ? (unsigned)(prow * Sq + cc * 8)
                      : (unsigned)(prow * 64 + cc * 8);
    }

    const size_t qoff = ((size_t)bh * Sq + qt * 64 + w * 16 + ml) * Dq + quad * 8;
    bfv8 aQh[2], aQl[2];
    #pragma unroll
    for (int ks = 0; ks < 2; ++ks) {
        aQh[ks] = *(const bfv8*)(qhb + qoff + ks * 32);
        aQl[ks] = *(const bfv8*)(qlb + qoff + ks * 32);
    }

    float m_st[4], l_st[4];
    f32x4 O[4];
    #pragma unroll
    for (int r = 0; r < 4; ++r) { m_st[r] = -INFINITY; l_st[r] = 0.f; }
    #pragma unroll
    for (int ng = 0; ng < 4; ++ng) O[ng] = (f32x4){0.f, 0.f, 0.f, 0.f};

    for (int kt = 0; kt < 32; ++kt) {
        __syncthreads();
        {
            const unsigned short* gt = gsrc + gbase + (isV ? kt * 64 : kt * 4096);
            #pragma unroll
            for (int i = 0; i < 8; ++i)
                gld_lds16(gt + goff[i], &kv_s[w][i * 512]);
        }
        __syncthreads();

        f32x4 S[4];
        #pragma unroll
        for (int ng = 0; ng < 4; ++ng) {
            f32x4 acc = (f32x4){0.f, 0.f, 0.f, 0.f};
            #pragma unroll
            for (int ks = 0; ks < 2; ++ks) {
                const int rr = ng * 16 + ml;
                const int off = rr * 64 + ((((ks * 4 + quad) ^ (rr & 7))) << 3);
                bfv8 bKh = *(const bfv8*)&kv_s[0][off];
                bfv8 bKl = *(const bfv8*)&kv_s[1][off];
                acc = MFMA16(aQh[ks], bKh, acc);
                acc = MFMA16(aQl[ks], bKh, acc);
                acc = MFMA16(aQh[ks], bKl, acc);
            }
            S[ng] = acc;
        }

        float nm[4], alpha[4];
        #pragma unroll
        for (int r = 0; r < 4; ++r) {
            float mx = fmaxf(fmaxf(S[0][r], S[1][r]), fmaxf(S[2][r], S[3][r]));
            #pragma unroll
            for (int off = 1; off < 16; off <<= 1)
                mx = fmaxf(mx, __shfl_xor(mx, off, 64));
            nm[r] = fmaxf(m_st[r], mx);
            alpha[r] = __expf(m_st[r] - nm[r]);
            m_st[r] = nm[r];
            O[0][r] *= alpha[r]; O[1][r] *= alpha[r];
            O[2][r] *= alpha[r]; O[3][r] *= alpha[r];
        }

        float ps[4] = {0.f, 0.f, 0.f, 0.f};
        #pragma unroll
        for (int ksP = 0; ksP < 2; ++ksP) {
            #pragma unroll
            for (int g2 = 0; g2 < 2; ++g2) {
                const int ng = ksP * 2 + g2;
                #pragma unroll
                for (int r = 0; r < 4; ++r) {
                    float p = __expf(S[ng][r] - nm[r]);
                    ps[r] += p;
                    unsigned short ph = bfbits(p);
                    unsigned short pl = lobits(p, ph);
                    pbuf[w][quad * 4 + r][g2 * 16 + ml] =
                        (unsigned int)ph | ((unsigned int)pl << 16);
                }
            }
            bfv8 aPh, aPl;
            {
                const unsigned int* src = &pbuf[w][ml][quad * 8];
                uint4 w0 = *(const uint4*)src;
                uint4 w1 = *(const uint4*)(src + 4);
                union { unsigned short s[8]; bfv8 v; } hu, lu;
                unsigned int arr8[8] = {w0.x, w0.y, w0.z, w0.w,
                                        w1.x, w1.y, w1.z, w1.w};
                #pragma unroll
                for (int j = 0; j < 8; ++j) {
                    hu.s[j] = (unsigned short)(arr8[j] & 0xffffu);
                    lu.s[j] = (unsigned short)(arr8[j] >> 16);
                }
                aPh = hu.v;
                aPl = lu.v;
            }
            #pragma unroll
            for (int ngd = 0; ngd < 4; ++ngd) {
                const int rr = ngd * 16 + ml;
                const int off = rr * 64 + ((((ksP * 4 + quad) ^ (rr & 7))) << 3);
                bfv8 bVh = *(const bfv8*)&kv_s[2][off];
                bfv8 bVl = *(const bfv8*)&kv_s[3][off];
                O[ngd] = MFMA16(aPh, bVh, O[ngd]);
                O[ngd] = MFMA16(aPl, bVh, O[ngd]);
                O[ngd] = MFMA16(aPh, bVl, O[ngd]);
            }
        }
        #pragma unroll
        for (int r = 0; r < 4; ++r) {
            #pragma unroll
            for (int off = 1; off < 16; off <<= 1)
                ps[r] += __shfl_xor(ps[r], off, 64);
            l_st[r] = l_st[r] * alpha[r] + ps[r];
        }
    }

    const int bb = bh / Hq, hh = bh % Hq;
    #pragma unroll
    for (int r = 0; r < 4; ++r) {
        const float il = 1.0f / l_st[r];
        const int srow = qt * 64 + w * 16 + quad * 4 + r;
        const size_t obase = ((size_t)bb * Sq + srow) * Cq + hh * 64 + ml;
        #pragma unroll
        for (int ng = 0; ng < 4; ++ng)
            attn[obase + ng * 16] = O[ng][r] * il;
    }
}

// ---------------------------------------------------------------------------
extern "C" void kernel_launch(void* const* d_in, const int* in_sizes, int n_in,
                              void* d_out, int out_size, void* d_ws, size_t ws_size,
                              hipStream_t stream) {
    const float* x     = (const float*)d_in[0];
    const float* Wqkv  = (const float*)d_in[1];
    const float* Wproj = (const float*)d_in[2];
    const float* bproj = (const float*)d_in[3];
    float* out = (float*)d_out;

    const size_t BHSD = (size_t)Bq * Hq * Sq * Dq;   // 3,145,728
    char* p = (char*)d_ws;
    unsigned short* qhb  = (unsigned short*)p; p += BHSD * 2;
    unsigned short* qlb  = (unsigned short*)p; p += BHSD * 2;
    unsigned short* khb  = (unsigned short*)p; p += BHSD * 2;
    unsigned short* klb  = (unsigned short*)p; p += BHSD * 2;
    unsigned short* vThb = (unsigned short*)p; p += BHSD * 2;
    unsigned short* vTlb = (unsigned short*)p; p += BHSD * 2;
    float*  attn  = (float*)p;  p += BHSD * 4;
    float*  ctab  = (float*)p;  p += (size_t)Sq * 32 * 4;
    float*  stab  = (float*)p;  p += (size_t)Sq * 32 * 4;
    // total ws use ~50 MB

    freq_kernel<<<256, 256, 0, stream>>>(ctab, stab);
    gemm_mfma_kernel<0><<<dim3(18, 32), 256, 0, stream>>>(
        x, Wqkv, ctab, stab, qhb, qlb, khb, klb, vThb, vTlb, nullptr, nullptr);
    attn_mfma_kernel<<<dim3(32 * 24), 256, 0, stream>>>(
        qhb, qlb, khb, klb, vThb, vTlb, attn);
    gemm_mfma_kernel<1><<<dim3(6, 32), 256, 0, stream>>>(
        attn, Wproj, ctab, stab, nullptr, nullptr, nullptr, nullptr, nullptr, nullptr,
        out, bproj);
}

// Round 9
// 292.298 us; speedup vs baseline: 2.7904x; 1.1054x over previous
//
#include <hip/hip_runtime.h>
#include <math.h>

// Problem constants
#define Bq 2
#define Sq 2048
#define Cq 768
#define Hq 12
#define Dq 64

typedef __bf16 bfv8 __attribute__((ext_vector_type(8)));
typedef float f32x4 __attribute__((ext_vector_type(4)));
#define MFMA16(a, b, c) __builtin_amdgcn_mfma_f32_16x16x32_bf16(a, b, c, 0, 0, 0)

static __device__ inline unsigned short bfbits(float x) {
    __bf16 b = (__bf16)x;
    return __builtin_bit_cast(unsigned short, b);
}
static __device__ inline float bf2f(unsigned short b) {
    return (float)__builtin_bit_cast(__bf16, b);
}
static __device__ inline unsigned short lobits(float x, unsigned short hb) {
    return bfbits(x - bf2f(hb));
}

// async 16B global->LDS copy; lds dest is wave-uniform base (+lane*16 by HW)
static __device__ inline void gld_lds16(const unsigned short* g, unsigned short* l) {
    __builtin_amdgcn_global_load_lds(
        (const __attribute__((address_space(1))) unsigned int*)g,
        (__attribute__((address_space(3))) unsigned int*)l, 16, 0, 0);
}

// DPP butterfly reductions over 16 lanes (VALU pipe, no LDS traffic).
// masks {1,2,7,15} generate the 4-bit xor group: quad_perm(1,0,3,2)=0xB1,
// quad_perm(2,3,0,1)=0x4E, row_half_mirror=0x141, row_mirror=0x140.
template <int CTRL>
static __device__ inline float dppmax(float x) {
    int y = __builtin_amdgcn_mov_dpp(__builtin_bit_cast(int, x), CTRL, 0xF, 0xF, true);
    return fmaxf(x, __builtin_bit_cast(float, y));
}
template <int CTRL>
static __device__ inline float dppadd(float x) {
    int y = __builtin_amdgcn_mov_dpp(__builtin_bit_cast(int, x), CTRL, 0xF, 0xF, true);
    return x + __builtin_bit_cast(float, y);
}
static __device__ inline float redmax16(float x) {
    x = dppmax<0xB1>(x); x = dppmax<0x4E>(x);
    x = dppmax<0x141>(x); x = dppmax<0x140>(x);
    return x;
}
static __device__ inline float redsum16(float x) {
    x = dppadd<0xB1>(x); x = dppadd<0x4E>(x);
    x = dppadd<0x141>(x); x = dppadd<0x140>(x);
    return x;
}

// ---------------------------------------------------------------------------
// Kernel 0: RoPE cos/sin tables  [S][32] each, fp64-accurate
// ---------------------------------------------------------------------------
__global__ void freq_kernel(float* __restrict__ ctab, float* __restrict__ stab) {
    int idx = blockIdx.x * blockDim.x + threadIdx.x;   // 0..65535
    int s = idx >> 5;
    int i = idx & 31;
    double f = (double)s * exp(-(double)i * 0.28782313662425573); // ln(1e4)/32
    ctab[idx] = (float)cos(f);
    stab[idx] = (float)sin(f);
}

// ---------------------------------------------------------------------------
// Kernel 1: fp32 -> paired bf16 hi/lo split.  dst row = [hi 768 | lo 768].
// Segments: x (4096x768), Wqkv (2304x768), Wproj (768x768).
// ---------------------------------------------------------------------------
#define XN (4096 * 768)
#define WQN (2304 * 768)
#define WPN (768 * 768)
__global__ __launch_bounds__(256) void split_kernel(
    const float* __restrict__ x, const float* __restrict__ wq,
    const float* __restrict__ wp,
    unsigned short* __restrict__ xs, unsigned short* __restrict__ wqs,
    unsigned short* __restrict__ wps)
{
    const int e4 = (blockIdx.x * 256 + threadIdx.x) * 4;
    const float* src; unsigned short* dst; int e;
    if (e4 < XN)            { src = x;  dst = xs;  e = e4; }
    else if (e4 < XN + WQN) { src = wq; dst = wqs; e = e4 - XN; }
    else                    { src = wp; dst = wps; e = e4 - XN - WQN; }
    const int r = e / Cq, c = e % Cq;
    float4 v = *(const float4*)(src + e);
    const float* vf = (const float*)&v;
    unsigned short h[4], l[4];
    #pragma unroll
    for (int j = 0; j < 4; ++j) {
        h[j] = bfbits(vf[j]);
        l[j] = lobits(vf[j], h[j]);
    }
    *(ushort4*)&dst[(size_t)r * 1536 + c]       = *(ushort4*)h;
    *(ushort4*)&dst[(size_t)r * 1536 + 768 + c] = *(ushort4*)l;
}

// ---------------------------------------------------------------------------
// MFMA NT GEMM on pre-split paired inputs: out[m][n] = sum_k A[m][k]B[n][k].
// A,B: paired bf16 [rows][hi 768 | lo 768]. 128x128 tile, BK=32, 4 waves 2x2,
// 4x4 acc/wave, 3-term split (hh + lh + hl). Staging via global_load_lds w=16
// (zero VALU); LDS rows 64 shorts with 16B XOR swizzle (chunk c at c^(row&7))
// -> frag ds_read_b128 at 2-way banks (free). 32 KB LDS.
// MODE 0: QKV + RoPE epilogue -> q,k paired [B,H,S,128]; v paired-transposed
//         [B,H,D, hi 2048 | lo 2048]; q pre-scaled 1/8.
// MODE 1: proj + bias -> fp32 [M][768].
// ---------------------------------------------------------------------------
template <int MODE>
__global__ __launch_bounds__(256) void gemm_mfma_kernel(
    const unsigned short* __restrict__ Apr, const unsigned short* __restrict__ Bpr,
    const float* __restrict__ ctab, const float* __restrict__ stab,
    unsigned short* __restrict__ qp, unsigned short* __restrict__ kp,
    unsigned short* __restrict__ vp,
    float* __restrict__ out0, const float* __restrict__ bias)
{
    __shared__ unsigned short sA[128 * 64];
    __shared__ unsigned short sB[128 * 64];

    const int t    = threadIdx.x;
    const int w    = t >> 6;
    const int lane = t & 63;
    const int ml   = lane & 15;
    const int quad = lane >> 4;
    const int wm   = w >> 1;
    const int wn   = w & 1;

    const int mBase = blockIdx.y * 128;
    const int nBase = blockIdx.x * 128;

    // staging role: waves 0,1 -> sA; waves 2,3 -> sB; wl picks row half
    const bool isB = (w >= 2);
    const unsigned short* gsrc = isB ? Bpr : Apr;
    unsigned short* sdst = isB ? sB : sA;
    const int wl    = w & 1;
    const int rbase = isB ? nBase : mBase;
    unsigned int goff[8];
    #pragma unroll
    for (int j = 0; j < 8; ++j) {
        const int J   = wl * 8 + j;
        const int row = J * 8 + (lane >> 3);
        const int pc  = lane & 7;
        const int lc  = pc ^ (row & 7);        // logical chunk: 0-3 hi, 4-7 lo
        goff[j] = (unsigned)((rbase + row) * 1536 + (lc & 3) * 8
                             + ((lc >> 2) & 1) * 768);
    }
    const int Jb = wl * 8;

    f32x4 acc[4][4];
    #pragma unroll
    for (int mi = 0; mi < 4; ++mi)
        #pragma unroll
        for (int ni = 0; ni < 4; ++ni)
            acc[mi][ni] = (f32x4){0.f, 0.f, 0.f, 0.f};

    for (int k0 = 0; k0 < Cq; k0 += 32) {
        __syncthreads();
        #pragma unroll
        for (int j = 0; j < 8; ++j)
            gld_lds16(gsrc + goff[j] + k0, sdst + (Jb + j) * 512);
        __syncthreads();

        bfv8 aFh[4], aFl[4], bFh[4], bFl[4];
        #pragma unroll
        for (int mi = 0; mi < 4; ++mi) {
            const int row = wm * 64 + mi * 16 + ml;
            aFh[mi] = *(const bfv8*)&sA[row * 64 + ((quad ^ (row & 7)) << 3)];
            aFl[mi] = *(const bfv8*)&sA[row * 64 + (((4 + quad) ^ (row & 7)) << 3)];
        }
        #pragma unroll
        for (int ni = 0; ni < 4; ++ni) {
            const int row = wn * 64 + ni * 16 + ml;
            bFh[ni] = *(const bfv8*)&sB[row * 64 + ((quad ^ (row & 7)) << 3)];
            bFl[ni] = *(const bfv8*)&sB[row * 64 + (((4 + quad) ^ (row & 7)) << 3)];
        }
        #pragma unroll
        for (int mi = 0; mi < 4; ++mi)
            #pragma unroll
            for (int ni = 0; ni < 4; ++ni) {
                acc[mi][ni] = MFMA16(aFh[mi], bFh[ni], acc[mi][ni]);
                acc[mi][ni] = MFMA16(aFl[mi], bFh[ni], acc[mi][ni]);
                acc[mi][ni] = MFMA16(aFh[mi], bFl[ni], acc[mi][ni]);
            }
    }

    // ---- epilogue (C-layout: row = quad*4 + r, col = ml) ----
    if (MODE == 0) {
        const int which = nBase / Cq;   // 0=q 1=k 2=v (128 | 768 -> uniform)
        #pragma unroll
        for (int mi = 0; mi < 4; ++mi) {
            const int gm = mBase + wm * 64 + mi * 16 + quad * 4;  // + r
            const int bb = gm >> 11;
            const int s0 = gm & 2047;
            #pragma unroll
            for (int ni = 0; ni < 4; ++ni) {
                const int gn = nBase + wn * 64 + ni * 16 + ml;
                const int c  = gn - which * Cq;
                const int hh = c >> 6;
                const int dd = c & 63;
                if (which < 2) {
                    unsigned short* dstp = (which == 0) ? qp : kp;
                    #pragma unroll
                    for (int r = 0; r < 4; ++r) {
                        float val = acc[mi][ni][r];
                        float pv  = __shfl_xor(val, 1, 64);   // d-pair partner
                        const int fi = (s0 + r) * 32 + (dd >> 1);
                        float c0 = ctab[fi], sn = stab[fi];
                        float o = (dd & 1) ? (val * c0 + pv * sn)
                                           : (val * c0 - pv * sn);
                        if (which == 0) o *= 0.125f;          // fold 64^-0.5
                        unsigned short h0 = bfbits(o);
                        const size_t ob =
                            ((size_t)(bb * Hq + hh) * Sq + s0 + r) * 128 + dd;
                        dstp[ob]      = h0;
                        dstp[ob + 64] = lobits(o, h0);
                    }
                } else {
                    unsigned short hv[4], lv[4];
                    #pragma unroll
                    for (int r = 0; r < 4; ++r) {
                        float o = acc[mi][ni][r];
                        hv[r] = bfbits(o);
                        lv[r] = lobits(o, hv[r]);
                    }
                    const size_t oT =
                        ((size_t)(bb * Hq + hh) * Dq + dd) * 4096 + s0;
                    *(ushort4*)&vp[oT]        = *(ushort4*)hv;
                    *(ushort4*)&vp[oT + 2048] = *(ushort4*)lv;
                }
            }
        }
    } else {
        #pragma unroll
        for (int mi = 0; mi < 4; ++mi) {
            const int gm = mBase + wm * 64 + mi * 16 + quad * 4;
            #pragma unroll
            for (int ni = 0; ni < 4; ++ni) {
                const int gn = nBase + wn * 64 + ni * 16 + ml;
                const float bz = bias[gn];
                #pragma unroll
                for (int r = 0; r < 4; ++r)
                    out0[(size_t)(gm + r) * Cq + gn] = acc[mi][ni][r] + bz;
            }
        }
    }
}

// ---------------------------------------------------------------------------
// Kernel 2: MFMA flash attention, bf16 3-term split, paired K/V layouts.
// Grid 768 = 32 qt x 24 bh (XCD = bh%8). K tile (64x[hi64|lo64]) and V tile
// staged by wave pairs via global_load_lds; 16B XOR swizzle (chunk^(row&15))
// on the global address; softmax reductions via DPP (VALU, no DS traffic).
// LDS 41 KB -> 3 blocks/CU.
// ---------------------------------------------------------------------------
__global__ __launch_bounds__(256, 3) void attn_mfma_kernel(
    const unsigned short* __restrict__ qp, const unsigned short* __restrict__ kp,
    const unsigned short* __restrict__ vp, unsigned short* __restrict__ attns)
{
    __shared__ unsigned short k_s[64 * 128];   // 16 KB: rows=key, [hi64|lo64]
    __shared__ unsigned short v_s[64 * 128];   // 16 KB: rows=d,  [hi64|lo64]
    __shared__ unsigned int   pbuf[4][16][36];

    const int t    = threadIdx.x;
    const int w    = t >> 6;
    const int lane = t & 63;
    const int ml   = lane & 15;
    const int quad = lane >> 4;
    const int bi   = blockIdx.x;
    const int bh   = bi % 24;               // XCD = bh % 8
    const int qt   = bi / 24;               // 0..31

    // staging: waves 0,1 -> K; waves 2,3 -> V; wl picks row half
    const bool isV = (w >= 2);
    const unsigned short* gsrc = isV ? vp : kp;
    unsigned short* sdst = isV ? v_s : k_s;
    const int wl = w & 1;
    const size_t gb = isV ? (size_t)bh * Dq * 4096 : (size_t)bh * Sq * 128;
    const int kinc = isV ? 64 : 8192;       // per-kt global advance (shorts)
    unsigned int goff[8];
    #pragma unroll
    for (int j = 0; j < 8; ++j) {
        const int J   = wl * 8 + j;
        const int row = J * 4 + (lane >> 4);
        const int pc  = lane & 15;
        const int lc  = pc ^ (row & 15);    // logical chunk: 0-7 hi, 8-15 lo
        goff[j] = isV ? (unsigned)(row * 4096 + ((lc >> 3) & 1) * 2048
                                   + (lc & 7) * 8)
                      : (unsigned)(row * 128 + lc * 8);
    }
    const int Jb = wl * 8;

    // ---- Q fragments (A-layout), paired rows [hi64|lo64] ----
    const size_t qrow = ((size_t)bh * Sq + qt * 64 + w * 16 + ml) * 128;
    bfv8 aQh[2], aQl[2];
    #pragma unroll
    for (int ks = 0; ks < 2; ++ks) {
        aQh[ks] = *(const bfv8*)(qp + qrow + ks * 32 + quad * 8);
        aQl[ks] = *(const bfv8*)(qp + qrow + 64 + ks * 32 + quad * 8);
    }

    float m_st[4], l_st[4];
    f32x4 O[4];
    #pragma unroll
    for (int r = 0; r < 4; ++r) { m_st[r] = -INFINITY; l_st[r] = 0.f; }
    #pragma unroll
    for (int ng = 0; ng < 4; ++ng) O[ng] = (f32x4){0.f, 0.f, 0.f, 0.f};

    for (int kt = 0; kt < 32; ++kt) {
        __syncthreads();
        {
            const unsigned short* gt = gsrc + gb + (size_t)kt * kinc;
            #pragma unroll
            for (int j = 0; j < 8; ++j)
                gld_lds16(gt + goff[j], sdst + (Jb + j) * 512);
        }
        __syncthreads();

        // ---- scores S = Q K^T (scale pre-folded into q) ----
        f32x4 S[4];
        #pragma unroll
        for (int ng = 0; ng < 4; ++ng) {
            f32x4 acc = (f32x4){0.f, 0.f, 0.f, 0.f};
            #pragma unroll
            for (int ks = 0; ks < 2; ++ks) {
                const int rr = ng * 16 + ml;
                const int lcH = ks * 4 + quad;
                bfv8 bKh = *(const bfv8*)&k_s[rr * 128 + ((lcH ^ (rr & 15)) << 3)];
                bfv8 bKl = *(const bfv8*)&k_s[rr * 128 + (((8 + lcH) ^ (rr & 15)) << 3)];
                acc = MFMA16(aQh[ks], bKh, acc);
                acc = MFMA16(aQl[ks], bKh, acc);
                acc = MFMA16(aQh[ks], bKl, acc);
            }
            S[ng] = acc;
        }

        // ---- online softmax state update (DPP reductions) ----
        float nm[4], alpha[4];
        #pragma unroll
        for (int r = 0; r < 4; ++r) {
            float mx = fmaxf(fmaxf(S[0][r], S[1][r]), fmaxf(S[2][r], S[3][r]));
            mx = redmax16(mx);
            nm[r] = fmaxf(m_st[r], mx);
            alpha[r] = __expf(m_st[r] - nm[r]);
            m_st[r] = nm[r];
            O[0][r] *= alpha[r]; O[1][r] *= alpha[r];
            O[2][r] *= alpha[r]; O[3][r] *= alpha[r];
        }

        // ---- two key-half passes: exp -> pbuf -> A-frag -> PV ----
        float ps[4] = {0.f, 0.f, 0.f, 0.f};
        #pragma unroll
        for (int ksP = 0; ksP < 2; ++ksP) {
            #pragma unroll
            for (int g2 = 0; g2 < 2; ++g2) {
                const int ng = ksP * 2 + g2;
                #pragma unroll
                for (int r = 0; r < 4; ++r) {
                    float p = __expf(S[ng][r] - nm[r]);
                    ps[r] += p;
                    unsigned short ph = bfbits(p);
                    unsigned short pl = lobits(p, ph);
                    pbuf[w][quad * 4 + r][g2 * 16 + ml] =
                        (unsigned int)ph | ((unsigned int)pl << 16);
                }
            }
            bfv8 aPh, aPl;
            {
                const unsigned int* src = &pbuf[w][ml][quad * 8];
                uint4 w0 = *(const uint4*)src;
                uint4 w1 = *(const uint4*)(src + 4);
                union { unsigned short s[8]; bfv8 v; } hu, lu;
                unsigned int arr8[8] = {w0.x, w0.y, w0.z, w0.w,
                                        w1.x, w1.y, w1.z, w1.w};
                #pragma unroll
                for (int j = 0; j < 8; ++j) {
                    hu.s[j] = (unsigned short)(arr8[j] & 0xffffu);
                    lu.s[j] = (unsigned short)(arr8[j] >> 16);
                }
                aPh = hu.v;
                aPl = lu.v;
            }
            #pragma unroll
            for (int ngd = 0; ngd < 4; ++ngd) {
                const int rr = ngd * 16 + ml;
                const int lcH = ksP * 4 + quad;
                bfv8 bVh = *(const bfv8*)&v_s[rr * 128 + ((lcH ^ (rr & 15)) << 3)];
                bfv8 bVl = *(const bfv8*)&v_s[rr * 128 + (((8 + lcH) ^ (rr & 15)) << 3)];
                O[ngd] = MFMA16(aPh, bVh, O[ngd]);
                O[ngd] = MFMA16(aPl, bVh, O[ngd]);
                O[ngd] = MFMA16(aPh, bVl, O[ngd]);
            }
        }
        #pragma unroll
        for (int r = 0; r < 4; ++r) {
            ps[r] = redsum16(ps[r]);
            l_st[r] = l_st[r] * alpha[r] + ps[r];
        }
    }

    // ---- epilogue: O /= l, write paired bf16 [4096][hi768|lo768] ----
    const int bb = bh / Hq, hh = bh % Hq;
    #pragma unroll
    for (int r = 0; r < 4; ++r) {
        const float il = 1.0f / l_st[r];
        const int srow = qt * 64 + w * 16 + quad * 4 + r;
        const size_t rowb = (size_t)(bb * Sq + srow) * 1536 + hh * 64 + ml;
        #pragma unroll
        for (int ng = 0; ng < 4; ++ng) {
            float o = O[ng][r] * il;
            unsigned short h0 = bfbits(o);
            attns[rowb + ng * 16]       = h0;
            attns[rowb + 768 + ng * 16] = lobits(o, h0);
        }
    }
}

// ---------------------------------------------------------------------------
extern "C" void kernel_launch(void* const* d_in, const int* in_sizes, int n_in,
                              void* d_out, int out_size, void* d_ws, size_t ws_size,
                              hipStream_t stream) {
    const float* x     = (const float*)d_in[0];
    const float* Wqkv  = (const float*)d_in[1];
    const float* Wproj = (const float*)d_in[2];
    const float* bproj = (const float*)d_in[3];
    float* out = (float*)d_out;

    char* p = (char*)d_ws;
    unsigned short* xs    = (unsigned short*)p; p += (size_t)4096 * 1536 * 2;
    unsigned short* wqs   = (unsigned short*)p; p += (size_t)2304 * 1536 * 2;
    unsigned short* wps   = (unsigned short*)p; p += (size_t)768  * 1536 * 2;
    unsigned short* qp    = (unsigned short*)p; p += (size_t)24 * 2048 * 128 * 2;
    unsigned short* kp    = (unsigned short*)p; p += (size_t)24 * 2048 * 128 * 2;
    unsigned short* vp    = (unsigned short*)p; p += (size_t)24 * 64 * 4096 * 2;
    unsigned short* attns = (unsigned short*)p; p += (size_t)4096 * 1536 * 2;
    float* ctab = (float*)p; p += (size_t)Sq * 32 * 4;
    float* stab = (float*)p; p += (size_t)Sq * 32 * 4;
    // total ws ~74 MB

    freq_kernel<<<256, 256, 0, stream>>>(ctab, stab);
    split_kernel<<<(XN + WQN + WPN) / 4 / 256, 256, 0, stream>>>(
        x, Wqkv, Wproj, xs, wqs, wps);
    gemm_mfma_kernel<0><<<dim3(18, 32), 256, 0, stream>>>(
        xs, wqs, ctab, stab, qp, kp, vp, nullptr, nullptr);
    attn_mfma_kernel<<<dim3(32 * 24), 256, 0, stream>>>(qp, kp, vp, attns);
    gemm_mfma_kernel<1><<<dim3(6, 32), 256, 0, stream>>>(
        attns, wps, ctab, stab, nullptr, nullptr, nullptr, out, bproj);
}

// Round 10
// 292.153 us; speedup vs baseline: 2.7918x; 1.0005x over previous
//
#include <hip/hip_runtime.h>
#include <math.h>

// Problem constants
#define Bq 2
#define Sq 2048
#define Cq 768
#define Hq 12
#define Dq 64

#define PANEL_SHORTS 196608   // 24 steps x 8192 shorts (128 rows x [hi32|lo32])
#define PANELS_X  32
#define PANELS_WQ 18
#define PANELS_WP 6

typedef __bf16 bfv8 __attribute__((ext_vector_type(8)));
typedef float f32x4 __attribute__((ext_vector_type(4)));
#define MFMA16(a, b, c) __builtin_amdgcn_mfma_f32_16x16x32_bf16(a, b, c, 0, 0, 0)

static __device__ inline unsigned short bfbits(float x) {
    __bf16 b = (__bf16)x;
    return __builtin_bit_cast(unsigned short, b);
}
static __device__ inline float bf2f(unsigned short b) {
    return (float)__builtin_bit_cast(__bf16, b);
}
static __device__ inline unsigned short lobits(float x, unsigned short hb) {
    return bfbits(x - bf2f(hb));
}

// async 16B global->LDS copy; lds dest is wave-uniform base (+lane*16 by HW)
static __device__ inline void gld_lds16(const unsigned short* g, unsigned short* l) {
    __builtin_amdgcn_global_load_lds(
        (const __attribute__((address_space(1))) unsigned int*)g,
        (__attribute__((address_space(3))) unsigned int*)l, 16, 0, 0);
}

// DPP butterfly reductions over 16 lanes (VALU pipe, no LDS traffic).
template <int CTRL>
static __device__ inline float dppmax(float x) {
    int y = __builtin_amdgcn_mov_dpp(__builtin_bit_cast(int, x), CTRL, 0xF, 0xF, true);
    return fmaxf(x, __builtin_bit_cast(float, y));
}
template <int CTRL>
static __device__ inline float dppadd(float x) {
    int y = __builtin_amdgcn_mov_dpp(__builtin_bit_cast(int, x), CTRL, 0xF, 0xF, true);
    return x + __builtin_bit_cast(float, y);
}
static __device__ inline float redmax16(float x) {
    x = dppmax<0xB1>(x); x = dppmax<0x4E>(x);
    x = dppmax<0x141>(x); x = dppmax<0x140>(x);
    return x;
}
static __device__ inline float redsum16(float x) {
    x = dppadd<0xB1>(x); x = dppadd<0x4E>(x);
    x = dppadd<0x141>(x); x = dppadd<0x140>(x);
    return x;
}

// ---------------------------------------------------------------------------
// Kernel 0: RoPE cos/sin tables  [S][32] each, fp64-accurate
// ---------------------------------------------------------------------------
__global__ void freq_kernel(float* __restrict__ ctab, float* __restrict__ stab) {
    int idx = blockIdx.x * blockDim.x + threadIdx.x;   // 0..65535
    int s = idx >> 5;
    int i = idx & 31;
    double f = (double)s * exp(-(double)i * 0.28782313662425573); // ln(1e4)/32
    ctab[idx] = (float)cos(f);
    stab[idx] = (float)sin(f);
}

// ---------------------------------------------------------------------------
// Kernel 1: fp32 -> bf16 hi/lo split into GEMM panel-blocked, PRE-SWIZZLED
// layout. Panel = 128 rows; per BK=32 step a 16 KB block stored in the exact
// LDS image the GEMM DMAs: pos = J*512 + lane*8, row = J*8+(lane>>3),
// phys chunk pc = lane&7 holds logical chunk lc = pc ^ (row&7)
// (lc&3 = k-subchunk, lc>>2 = hi/lo). GEMM DMA becomes an identity copy.
// ---------------------------------------------------------------------------
__global__ __launch_bounds__(256) void split_kernel(
    const float* __restrict__ x, const float* __restrict__ wq,
    const float* __restrict__ wp,
    unsigned short* __restrict__ xs, unsigned short* __restrict__ wqs,
    unsigned short* __restrict__ wps)
{
    const int cid  = blockIdx.x * 256 + threadIdx.x;  // 16B output chunk id
    const int panel = cid / 24576;                    // PANEL_SHORTS/8
    const int pos8  = cid % 24576;
    const int step = pos8 >> 10;
    const int rem  = pos8 & 1023;
    const int J    = rem >> 6;
    const int lane = rem & 63;
    const int rowp = J * 8 + (lane >> 3);
    const int lc   = (lane & 7) ^ (rowp & 7);
    const int k    = step * 32 + (lc & 3) * 8;
    const int islo = lc >> 2;
    const float* src; unsigned short* dst; int prow;
    if (panel < PANELS_X) {
        src = x;  dst = xs;  prow = panel;
    } else if (panel < PANELS_X + PANELS_WQ) {
        src = wq; dst = wqs; prow = panel - PANELS_X;
    } else {
        src = wp; dst = wps; prow = panel - PANELS_X - PANELS_WQ;
    }
    const int row = prow * 128 + rowp;
    float4 v0 = *(const float4*)(src + (size_t)row * Cq + k);
    float4 v1 = *(const float4*)(src + (size_t)row * Cq + k + 4);
    float vf[8] = {v0.x, v0.y, v0.z, v0.w, v1.x, v1.y, v1.z, v1.w};
    unsigned short o[8];
    #pragma unroll
    for (int j = 0; j < 8; ++j) {
        unsigned short h = bfbits(vf[j]);
        o[j] = islo ? lobits(vf[j], h) : h;
    }
    *(uint4*)&dst[(size_t)prow * PANEL_SHORTS + (size_t)pos8 * 8] = *(uint4*)o;
}

// ---------------------------------------------------------------------------
// MFMA NT GEMM on panel-blocked pre-swizzled inputs. 128x128 tile, BK=32,
// 4 waves 2x2, 4x4 acc/wave, 3-term split. Staging = identity global_load_lds
// (1 KB contiguous per instruction). 32 KB LDS.
// MODE 0: QKV + RoPE epilogue. q -> paired [B,H,S,128] (hi64|lo64 per row);
//         k -> attn K blocked image [bh][kt][8192]; v -> attn V blocked image.
//         q pre-scaled 1/8.
// MODE 1: proj + bias -> fp32 [M][768].
// ---------------------------------------------------------------------------
template <int MODE>
__global__ __launch_bounds__(256) void gemm_mfma_kernel(
    const unsigned short* __restrict__ Apr, const unsigned short* __restrict__ Bpr,
    const float* __restrict__ ctab, const float* __restrict__ stab,
    unsigned short* __restrict__ qp, unsigned short* __restrict__ kp,
    unsigned short* __restrict__ vp,
    float* __restrict__ out0, const float* __restrict__ bias)
{
    __shared__ unsigned short sA[128 * 64];
    __shared__ unsigned short sB[128 * 64];

    const int t    = threadIdx.x;
    const int w    = t >> 6;
    const int lane = t & 63;
    const int ml   = lane & 15;
    const int quad = lane >> 4;
    const int wm   = w >> 1;
    const int wn   = w & 1;

    const int mBase = blockIdx.y * 128;
    const int nBase = blockIdx.x * 128;

    // staging role: waves 0,1 -> sA; waves 2,3 -> sB; wl picks 8KB half
    const bool isB = (w >= 2);
    const unsigned short* gpan = (isB ? Bpr : Apr)
        + (size_t)((isB ? nBase : mBase) >> 7) * PANEL_SHORTS;
    unsigned short* sdst = isB ? sB : sA;
    const int wl = w & 1;
    const int Jb = wl * 8;

    f32x4 acc[4][4];
    #pragma unroll
    for (int mi = 0; mi < 4; ++mi)
        #pragma unroll
        for (int ni = 0; ni < 4; ++ni)
            acc[mi][ni] = (f32x4){0.f, 0.f, 0.f, 0.f};

    for (int k0 = 0; k0 < Cq; k0 += 32) {
        const unsigned short* gt = gpan + (k0 >> 5) * 8192;
        __syncthreads();
        #pragma unroll
        for (int j = 0; j < 8; ++j)
            gld_lds16(gt + (Jb + j) * 512 + lane * 8, sdst + (Jb + j) * 512);
        __syncthreads();

        bfv8 aFh[4], aFl[4], bFh[4], bFl[4];
        #pragma unroll
        for (int mi = 0; mi < 4; ++mi) {
            const int row = wm * 64 + mi * 16 + ml;
            aFh[mi] = *(const bfv8*)&sA[row * 64 + ((quad ^ (row & 7)) << 3)];
            aFl[mi] = *(const bfv8*)&sA[row * 64 + (((4 + quad) ^ (row & 7)) << 3)];
        }
        #pragma unroll
        for (int ni = 0; ni < 4; ++ni) {
            const int row = wn * 64 + ni * 16 + ml;
            bFh[ni] = *(const bfv8*)&sB[row * 64 + ((quad ^ (row & 7)) << 3)];
            bFl[ni] = *(const bfv8*)&sB[row * 64 + (((4 + quad) ^ (row & 7)) << 3)];
        }
        #pragma unroll
        for (int mi = 0; mi < 4; ++mi)
            #pragma unroll
            for (int ni = 0; ni < 4; ++ni) {
                acc[mi][ni] = MFMA16(aFh[mi], bFh[ni], acc[mi][ni]);
                acc[mi][ni] = MFMA16(aFl[mi], bFh[ni], acc[mi][ni]);
                acc[mi][ni] = MFMA16(aFh[mi], bFl[ni], acc[mi][ni]);
            }
    }

    // ---- epilogue (C-layout: row = quad*4 + r, col = ml) ----
    if (MODE == 0) {
        const int which = nBase / Cq;   // 0=q 1=k 2=v
        #pragma unroll
        for (int mi = 0; mi < 4; ++mi) {
            const int gm = mBase + wm * 64 + mi * 16 + quad * 4;  // + r
            const int bb = gm >> 11;
            const int s0 = gm & 2047;
            #pragma unroll
            for (int ni = 0; ni < 4; ++ni) {
                const int gn = nBase + wn * 64 + ni * 16 + ml;
                const int c  = gn - which * Cq;
                const int hh = c >> 6;
                const int dd = c & 63;
                if (which < 2) {
                    #pragma unroll
                    for (int r = 0; r < 4; ++r) {
                        float val = acc[mi][ni][r];
                        float pv  = __shfl_xor(val, 1, 64);   // d-pair partner
                        const int fi = (s0 + r) * 32 + (dd >> 1);
                        float c0 = ctab[fi], sn = stab[fi];
                        float o = (dd & 1) ? (val * c0 + pv * sn)
                                           : (val * c0 - pv * sn);
                        unsigned short h0, l0;
                        if (which == 0) {
                            o *= 0.125f;                      // fold 64^-0.5
                            h0 = bfbits(o); l0 = lobits(o, h0);
                            const size_t ob =
                                ((size_t)(bb * Hq + hh) * Sq + s0 + r) * 128 + dd;
                            qp[ob]      = h0;
                            qp[ob + 64] = l0;
                        } else {
                            h0 = bfbits(o); l0 = lobits(o, h0);
                            // attn K blocked image
                            const int ss = s0 + r, rr = ss & 63, kt2 = ss >> 6;
                            const size_t pb =
                                ((size_t)(bb * Hq + hh) * 32 + kt2) * 8192
                                + (rr >> 2) * 512 + (rr & 3) * 128;
                            const int pch = (dd >> 3) ^ (rr & 15);
                            const int pcl = (8 + (dd >> 3)) ^ (rr & 15);
                            kp[pb + pch * 8 + (dd & 7)] = h0;
                            kp[pb + pcl * 8 + (dd & 7)] = l0;
                        }
                    }
                } else {
                    // attn V blocked image: row = d, chunks over keys
                    unsigned short hv[4], lv[4];
                    #pragma unroll
                    for (int r = 0; r < 4; ++r) {
                        float o = acc[mi][ni][r];
                        hv[r] = bfbits(o);
                        lv[r] = lobits(o, hv[r]);
                    }
                    const int kt2 = s0 >> 6;
                    const int keypart = (s0 & 63) >> 3;   // same for r=0..3
                    const size_t pb =
                        ((size_t)(bb * Hq + hh) * 32 + kt2) * 8192
                        + (dd >> 2) * 512 + (dd & 3) * 128;
                    const int pch = keypart ^ (dd & 15);
                    const int pcl = (8 + keypart) ^ (dd & 15);
                    *(ushort4*)&vp[pb + pch * 8 + (s0 & 7)] = *(ushort4*)hv;
                    *(ushort4*)&vp[pb + pcl * 8 + (s0 & 7)] = *(ushort4*)lv;
                }
            }
        }
    } else {
        #pragma unroll
        for (int mi = 0; mi < 4; ++mi) {
            const int gm = mBase + wm * 64 + mi * 16 + quad * 4;
            #pragma unroll
            for (int ni = 0; ni < 4; ++ni) {
                const int gn = nBase + wn * 64 + ni * 16 + ml;
                const float bz = bias[gn];
                #pragma unroll
                for (int r = 0; r < 4; ++r)
                    out0[(size_t)(gm + r) * Cq + gn] = acc[mi][ni][r] + bz;
            }
        }
    }
}

// ---------------------------------------------------------------------------
// Kernel 2: MFMA flash attention, bf16 3-term split. Grid 768 = 32 qt x 24 bh
// (XCD = bh%8). K/V tiles stored pre-swizzled & blocked -> identity DMA.
// Softmax reductions via DPP. Output written in proj-GEMM panel-blocked image.
// ---------------------------------------------------------------------------
__global__ __launch_bounds__(256, 3) void attn_mfma_kernel(
    const unsigned short* __restrict__ qp, const unsigned short* __restrict__ kp,
    const unsigned short* __restrict__ vp, unsigned short* __restrict__ attns)
{
    __shared__ unsigned short k_s[64 * 128];   // rows=key, [hi64|lo64] swizzled
    __shared__ unsigned short v_s[64 * 128];   // rows=d,   [hi64|lo64] swizzled
    __shared__ unsigned int   pbuf[4][16][36];

    const int t    = threadIdx.x;
    const int w    = t >> 6;
    const int lane = t & 63;
    const int ml   = lane & 15;
    const int quad = lane >> 4;
    const int bi   = blockIdx.x;
    const int bh   = bi % 24;               // XCD = bh % 8
    const int qt   = bi / 24;               // 0..31

    // staging: waves 0,1 -> K; waves 2,3 -> V; wl picks 8KB half
    const bool isV = (w >= 2);
    const unsigned short* gsrc = isV ? vp : kp;
    unsigned short* sdst = isV ? v_s : k_s;
    const int wl = w & 1;
    const int Jb = wl * 8;
    const size_t gb = (size_t)bh * 262144;  // 32 blocks x 8192 shorts

    // ---- Q fragments (A-layout), paired rows [hi64|lo64] ----
    const size_t qrow = ((size_t)bh * Sq + qt * 64 + w * 16 + ml) * 128;
    bfv8 aQh[2], aQl[2];
    #pragma unroll
    for (int ks = 0; ks < 2; ++ks) {
        aQh[ks] = *(const bfv8*)(qp + qrow + ks * 32 + quad * 8);
        aQl[ks] = *(const bfv8*)(qp + qrow + 64 + ks * 32 + quad * 8);
    }

    float m_st[4], l_st[4];
    f32x4 O[4];
    #pragma unroll
    for (int r = 0; r < 4; ++r) { m_st[r] = -INFINITY; l_st[r] = 0.f; }
    #pragma unroll
    for (int ng = 0; ng < 4; ++ng) O[ng] = (f32x4){0.f, 0.f, 0.f, 0.f};

    for (int kt = 0; kt < 32; ++kt) {
        __syncthreads();
        {
            const unsigned short* gt = gsrc + gb + (size_t)kt * 8192;
            #pragma unroll
            for (int j = 0; j < 8; ++j)
                gld_lds16(gt + (Jb + j) * 512 + lane * 8, sdst + (Jb + j) * 512);
        }
        __syncthreads();

        // ---- scores S = Q K^T (scale pre-folded into q) ----
        f32x4 S[4];
        #pragma unroll
        for (int ng = 0; ng < 4; ++ng) {
            f32x4 acc = (f32x4){0.f, 0.f, 0.f, 0.f};
            #pragma unroll
            for (int ks = 0; ks < 2; ++ks) {
                const int rr = ng * 16 + ml;
                const int lcH = ks * 4 + quad;
                bfv8 bKh = *(const bfv8*)&k_s[rr * 128 + ((lcH ^ (rr & 15)) << 3)];
                bfv8 bKl = *(const bfv8*)&k_s[rr * 128 + (((8 + lcH) ^ (rr & 15)) << 3)];
                acc = MFMA16(aQh[ks], bKh, acc);
                acc = MFMA16(aQl[ks], bKh, acc);
                acc = MFMA16(aQh[ks], bKl, acc);
            }
            S[ng] = acc;
        }

        // ---- online softmax state update (DPP reductions) ----
        float nm[4], alpha[4];
        #pragma unroll
        for (int r = 0; r < 4; ++r) {
            float mx = fmaxf(fmaxf(S[0][r], S[1][r]), fmaxf(S[2][r], S[3][r]));
            mx = redmax16(mx);
            nm[r] = fmaxf(m_st[r], mx);
            alpha[r] = __expf(m_st[r] - nm[r]);
            m_st[r] = nm[r];
            O[0][r] *= alpha[r]; O[1][r] *= alpha[r];
            O[2][r] *= alpha[r]; O[3][r] *= alpha[r];
        }

        // ---- two key-half passes: exp -> pbuf -> A-frag -> PV ----
        float ps[4] = {0.f, 0.f, 0.f, 0.f};
        #pragma unroll
        for (int ksP = 0; ksP < 2; ++ksP) {
            #pragma unroll
            for (int g2 = 0; g2 < 2; ++g2) {
                const int ng = ksP * 2 + g2;
                #pragma unroll
                for (int r = 0; r < 4; ++r) {
                    float p = __expf(S[ng][r] - nm[r]);
                    ps[r] += p;
                    unsigned short ph = bfbits(p);
                    unsigned short pl = lobits(p, ph);
                    pbuf[w][quad * 4 + r][g2 * 16 + ml] =
                        (unsigned int)ph | ((unsigned int)pl << 16);
                }
            }
            bfv8 aPh, aPl;
            {
                const unsigned int* src = &pbuf[w][ml][quad * 8];
                uint4 w0 = *(const uint4*)src;
                uint4 w1 = *(const uint4*)(src + 4);
                union { unsigned short s[8]; bfv8 v; } hu, lu;
                unsigned int arr8[8] = {w0.x, w0.y, w0.z, w0.w,
                                        w1.x, w1.y, w1.z, w1.w};
                #pragma unroll
                for (int j = 0; j < 8; ++j) {
                    hu.s[j] = (unsigned short)(arr8[j] & 0xffffu);
                    lu.s[j] = (unsigned short)(arr8[j] >> 16);
                }
                aPh = hu.v;
                aPl = lu.v;
            }
            #pragma unroll
            for (int ngd = 0; ngd < 4; ++ngd) {
                const int rr = ngd * 16 + ml;
                const int lcH = ksP * 4 + quad;
                bfv8 bVh = *(const bfv8*)&v_s[rr * 128 + ((lcH ^ (rr & 15)) << 3)];
                bfv8 bVl = *(const bfv8*)&v_s[rr * 128 + (((8 + lcH) ^ (rr & 15)) << 3)];
                O[ngd] = MFMA16(aPh, bVh, O[ngd]);
                O[ngd] = MFMA16(aPl, bVh, O[ngd]);
                O[ngd] = MFMA16(aPh, bVl, O[ngd]);
            }
        }
        #pragma unroll
        for (int r = 0; r < 4; ++r) {
            ps[r] = redsum16(ps[r]);
            l_st[r] = l_st[r] * alpha[r] + ps[r];
        }
    }

    // ---- epilogue: O /= l, write proj-GEMM panel-blocked hi/lo image ----
    const int bb = bh / Hq, hh = bh % Hq;
    #pragma unroll
    for (int r = 0; r < 4; ++r) {
        const float il = 1.0f / l_st[r];
        const int srow = qt * 64 + w * 16 + quad * 4 + r;
        const int m = bb * 2048 + srow;
        const int panel = m >> 7, r128 = m & 127;
        const size_t rbase = (size_t)panel * PANEL_SHORTS
                           + (r128 >> 3) * 512 + (r128 & 7) * 64;
        #pragma unroll
        for (int ng = 0; ng < 4; ++ng) {
            const int k = hh * 64 + ng * 16 + ml;
            float o = O[ng][r] * il;
            unsigned short h0 = bfbits(o);
            unsigned short l0 = lobits(o, h0);
            const int step = k >> 5;
            const int lch  = (k & 31) >> 3;
            const size_t sb = rbase + (size_t)step * 8192;
            attns[sb + ((lch ^ (r128 & 7)) << 3)       + (k & 7)] = h0;
            attns[sb + (((4 + lch) ^ (r128 & 7)) << 3) + (k & 7)] = l0;
        }
    }
}

// ---------------------------------------------------------------------------
extern "C" void kernel_launch(void* const* d_in, const int* in_sizes, int n_in,
                              void* d_out, int out_size, void* d_ws, size_t ws_size,
                              hipStream_t stream) {
    const float* x     = (const float*)d_in[0];
    const float* Wqkv  = (const float*)d_in[1];
    const float* Wproj = (const float*)d_in[2];
    const float* bproj = (const float*)d_in[3];
    float* out = (float*)d_out;

    char* p = (char*)d_ws;
    unsigned short* xs    = (unsigned short*)p; p += (size_t)PANELS_X  * PANEL_SHORTS * 2;
    unsigned short* wqs   = (unsigned short*)p; p += (size_t)PANELS_WQ * PANEL_SHORTS * 2;
    unsigned short* wps   = (unsigned short*)p; p += (size_t)PANELS_WP * PANEL_SHORTS * 2;
    unsigned short* qp    = (unsigned short*)p; p += (size_t)24 * 2048 * 128 * 2;
    unsigned short* kp    = (unsigned short*)p; p += (size_t)24 * 32 * 8192 * 2;
    unsigned short* vp    = (unsigned short*)p; p += (size_t)24 * 32 * 8192 * 2;
    unsigned short* attns = (unsigned short*)p; p += (size_t)PANELS_X * PANEL_SHORTS * 2;
    float* ctab = (float*)p; p += (size_t)Sq * 32 * 4;
    float* stab = (float*)p; p += (size_t)Sq * 32 * 4;
    // total ws ~73 MB

    freq_kernel<<<256, 256, 0, stream>>>(ctab, stab);
    split_kernel<<<(PANELS_X + PANELS_WQ + PANELS_WP) * 24576 / 256, 256, 0, stream>>>(
        x, Wqkv, Wproj, xs, wqs, wps);
    gemm_mfma_kernel<0><<<dim3(18, 32), 256, 0, stream>>>(
        xs, wqs, ctab, stab, qp, kp, vp, nullptr, nullptr);
    attn_mfma_kernel<<<dim3(32 * 24), 256, 0, stream>>>(qp, kp, vp, attns);
    gemm_mfma_kernel<1><<<dim3(6, 32), 256, 0, stream>>>(
        attns, wps, ctab, stab, nullptr, nullptr, nullptr, out, bproj);
}